// Round 1
// baseline (562.031 us; speedup 1.0000x reference)
//
#include <hip/hip_runtime.h>
#include <math.h>

#define BB 4
#define CC 64
#define CRR 8
#define NN 4096
#define NPIX 256
#define KSZ 7

// ---------------------------------------------------------------------------
// Pointwise conv: y[b,co,n] = sum_c W[co,c]*x[b,c,n] + bias[co]
// grid = B*16 (256 n per wg), block = 256
// ---------------------------------------------------------------------------
__global__ __launch_bounds__(256) void pw_conv_kernel(
    const float* __restrict__ x, const float* __restrict__ W,
    const float* __restrict__ bias, float* __restrict__ y, int CO)
{
    __shared__ float Ws[64 * 64];
    __shared__ float bs[64];
    int t = threadIdx.x;
    for (int i = t; i < CO * CC; i += 256) Ws[i] = W[i];
    if (t < CO) bs[t] = bias[t];
    __syncthreads();

    int gid = blockIdx.x;
    int b = gid >> 4;
    int n = ((gid & 15) << 8) + t;

    const float* xb = x + (size_t)b * CC * NN + n;
    float xv[CC];
#pragma unroll
    for (int c = 0; c < CC; ++c) xv[c] = xb[(size_t)c * NN];

    float* yb = y + (size_t)b * CO * NN + n;
    for (int co = 0; co < CO; co += 4) {
        float a0 = bs[co], a1 = bs[co + 1], a2 = bs[co + 2], a3 = bs[co + 3];
#pragma unroll
        for (int c = 0; c < CC; ++c) {
            float xc = xv[c];
            a0 = fmaf(Ws[(co + 0) * CC + c], xc, a0);
            a1 = fmaf(Ws[(co + 1) * CC + c], xc, a1);
            a2 = fmaf(Ws[(co + 2) * CC + c], xc, a2);
            a3 = fmaf(Ws[(co + 3) * CC + c], xc, a3);
        }
        yb[(size_t)(co + 0) * NN] = a0;
        yb[(size_t)(co + 1) * NN] = a1;
        yb[(size_t)(co + 2) * NN] = a2;
        yb[(size_t)(co + 3) * NN] = a3;
    }
}

// ---------------------------------------------------------------------------
// Fused spatial attention:
//   s[n,m] = sum_c f[c,n]*g[c,m];  beta = softmax_n(s);  x2[c,m] = sum_n hh[c,n]*beta[n,m]
// grid = B*64 (64 m per wg), block = 256. Two-pass (stats then PV).
// ---------------------------------------------------------------------------
__global__ __launch_bounds__(256) void attn_kernel(
    const float* __restrict__ f, const float* __restrict__ g,
    const float* __restrict__ hh, float* __restrict__ x2)
{
    __shared__ float gs[CRR][64];
    __shared__ float fs[CRR][64];
    __shared__ __align__(16) float hs[64][68];
    __shared__ __align__(16) float ps[64][68];
    __shared__ float Mrun[64], Lrun[64];
    __shared__ float pmax[4][64], psum[4][64];

    int t = threadIdx.x;
    int b = blockIdx.x >> 6;
    int m0 = (blockIdx.x & 63) << 6;

    const float* fb = f + (size_t)b * CRR * NN;
    const float* gb = g + (size_t)b * CRR * NN;
    const float* hb = hh + (size_t)b * CC * NN;

    {
        int n = t & 63; int c0 = (t >> 6) << 1;
        gs[c0][n]     = gb[(size_t)c0 * NN + m0 + n];
        gs[c0 + 1][n] = gb[(size_t)(c0 + 1) * NN + m0 + n];
    }
    if (t < 64) { Mrun[t] = -3e38f; Lrun[t] = 0.f; }
    __syncthreads();

    int tm = t & 15, tn = t >> 4;   // 16x16 blocks of 4x4 scores

    // ---------------- phase 1: softmax stats ----------------
    for (int nt = 0; nt < 64; ++nt) {
        int nbase = nt << 6;
        {
            int n = t & 63; int c0 = (t >> 6) << 1;
            fs[c0][n]     = fb[(size_t)c0 * NN + nbase + n];
            fs[c0 + 1][n] = fb[(size_t)(c0 + 1) * NN + nbase + n];
        }
        __syncthreads();

        float s[4][4];
#pragma unroll
        for (int i = 0; i < 4; ++i)
#pragma unroll
            for (int j = 0; j < 4; ++j) s[i][j] = 0.f;
#pragma unroll
        for (int c = 0; c < CRR; ++c) {
            float fv[4], gv[4];
#pragma unroll
            for (int i = 0; i < 4; ++i) fv[i] = fs[c][tn * 4 + i];
#pragma unroll
            for (int j = 0; j < 4; ++j) gv[j] = gs[c][tm * 4 + j];
#pragma unroll
            for (int i = 0; i < 4; ++i)
#pragma unroll
                for (int j = 0; j < 4; ++j) s[i][j] = fmaf(fv[i], gv[j], s[i][j]);
        }
#pragma unroll
        for (int i = 0; i < 4; ++i) {
            float4 v = make_float4(s[i][0], s[i][1], s[i][2], s[i][3]);
            *reinterpret_cast<float4*>(&ps[tn * 4 + i][tm * 4]) = v;
        }
        __syncthreads();

        {
            int mm = t & 63, grp = t >> 6;
            float v[16];
#pragma unroll
            for (int k = 0; k < 16; ++k) v[k] = ps[grp * 16 + k][mm];
            float pm = v[0];
#pragma unroll
            for (int k = 1; k < 16; ++k) pm = fmaxf(pm, v[k]);
            float sm_ = 0.f;
#pragma unroll
            for (int k = 0; k < 16; ++k) sm_ += __expf(v[k] - pm);
            pmax[grp][mm] = pm; psum[grp][mm] = sm_;
        }
        __syncthreads();
        if (t < 64) {
            float m01 = fmaxf(pmax[0][t], pmax[1][t]);
            float m23 = fmaxf(pmax[2][t], pmax[3][t]);
            float tmax = fmaxf(m01, m23);
            float ts = psum[0][t] * __expf(pmax[0][t] - tmax)
                     + psum[1][t] * __expf(pmax[1][t] - tmax)
                     + psum[2][t] * __expf(pmax[2][t] - tmax)
                     + psum[3][t] * __expf(pmax[3][t] - tmax);
            float Mo = Mrun[t];
            float Mn = fmaxf(Mo, tmax);
            Lrun[t] = Lrun[t] * __expf(Mo - Mn) + ts * __expf(tmax - Mn);
            Mrun[t] = Mn;
        }
        __syncthreads();
    }

    float Mloc[4];
#pragma unroll
    for (int j = 0; j < 4; ++j) Mloc[j] = Mrun[tm * 4 + j];

    int cb = t >> 4, mb = t & 15;
    float acc[4][4];
#pragma unroll
    for (int i = 0; i < 4; ++i)
#pragma unroll
        for (int j = 0; j < 4; ++j) acc[i][j] = 0.f;

    // ---------------- phase 2: P*V ----------------
    for (int nt = 0; nt < 64; ++nt) {
        int nbase = nt << 6;
        {
            int n = t & 63; int c0 = (t >> 6) << 1;
            fs[c0][n]     = fb[(size_t)c0 * NN + nbase + n];
            fs[c0 + 1][n] = fb[(size_t)(c0 + 1) * NN + nbase + n];
            int cc0 = t >> 6;
#pragma unroll
            for (int k = 0; k < 16; ++k) {
                int c = cc0 * 16 + k;
                hs[n][c] = hb[(size_t)c * NN + nbase + n];
            }
        }
        __syncthreads();

        float s[4][4];
#pragma unroll
        for (int i = 0; i < 4; ++i)
#pragma unroll
            for (int j = 0; j < 4; ++j) s[i][j] = 0.f;
#pragma unroll
        for (int c = 0; c < CRR; ++c) {
            float fv[4], gv[4];
#pragma unroll
            for (int i = 0; i < 4; ++i) fv[i] = fs[c][tn * 4 + i];
#pragma unroll
            for (int j = 0; j < 4; ++j) gv[j] = gs[c][tm * 4 + j];
#pragma unroll
            for (int i = 0; i < 4; ++i)
#pragma unroll
                for (int j = 0; j < 4; ++j) s[i][j] = fmaf(fv[i], gv[j], s[i][j]);
        }
#pragma unroll
        for (int i = 0; i < 4; ++i) {
            float4 v;
            v.x = __expf(s[i][0] - Mloc[0]);
            v.y = __expf(s[i][1] - Mloc[1]);
            v.z = __expf(s[i][2] - Mloc[2]);
            v.w = __expf(s[i][3] - Mloc[3]);
            *reinterpret_cast<float4*>(&ps[tn * 4 + i][tm * 4]) = v;
        }
        __syncthreads();

#pragma unroll 2
        for (int n = 0; n < 64; ++n) {
            float4 pv = *reinterpret_cast<const float4*>(&ps[n][mb * 4]);
            float4 hv = *reinterpret_cast<const float4*>(&hs[n][cb * 4]);
            acc[0][0] = fmaf(hv.x, pv.x, acc[0][0]);
            acc[0][1] = fmaf(hv.x, pv.y, acc[0][1]);
            acc[0][2] = fmaf(hv.x, pv.z, acc[0][2]);
            acc[0][3] = fmaf(hv.x, pv.w, acc[0][3]);
            acc[1][0] = fmaf(hv.y, pv.x, acc[1][0]);
            acc[1][1] = fmaf(hv.y, pv.y, acc[1][1]);
            acc[1][2] = fmaf(hv.y, pv.z, acc[1][2]);
            acc[1][3] = fmaf(hv.y, pv.w, acc[1][3]);
            acc[2][0] = fmaf(hv.z, pv.x, acc[2][0]);
            acc[2][1] = fmaf(hv.z, pv.y, acc[2][1]);
            acc[2][2] = fmaf(hv.z, pv.z, acc[2][2]);
            acc[2][3] = fmaf(hv.z, pv.w, acc[2][3]);
            acc[3][0] = fmaf(hv.w, pv.x, acc[3][0]);
            acc[3][1] = fmaf(hv.w, pv.y, acc[3][1]);
            acc[3][2] = fmaf(hv.w, pv.z, acc[3][2]);
            acc[3][3] = fmaf(hv.w, pv.w, acc[3][3]);
        }
        __syncthreads();
    }

    float rL[4];
#pragma unroll
    for (int j = 0; j < 4; ++j) rL[j] = 1.0f / Lrun[mb * 4 + j];

    float* xo = x2 + (size_t)b * CC * NN + m0 + mb * 4;
#pragma unroll
    for (int i = 0; i < 4; ++i) {
        int c = cb * 4 + i;
        float4 o = make_float4(acc[i][0] * rL[0], acc[i][1] * rL[1],
                               acc[i][2] * rL[2], acc[i][3] * rL[3]);
        *reinterpret_cast<float4*>(&xo[(size_t)c * NN]) = o;
    }
}

// ---------------------------------------------------------------------------
// 7x7 stride-4 pad-3 conv, both w4 and w5 branches.
// grid = B * 16 co-groups * 2 convs = 128, block = 256 (16x16 output plane).
// Each thread computes 4 consecutive co for its (oy,ox).
// ---------------------------------------------------------------------------
__global__ __launch_bounds__(256) void conv7_kernel(
    const float* __restrict__ x2,
    const float* __restrict__ w4, const float* __restrict__ b4,
    const float* __restrict__ w5, const float* __restrict__ b5,
    float* __restrict__ f2, float* __restrict__ g2)
{
    __shared__ float xs[4][64][17];   // input plane split by (ix mod 4)
    int t = threadIdx.x;
    int bid = blockIdx.x;
    int conv = bid & 1;
    int cog = (bid >> 1) & 15;
    int b = bid >> 5;
    int co0 = cog * 4;
    const float* W = conv ? w5 : w4;
    const float* bias = conv ? b5 : b4;
    float* y = conv ? g2 : f2;

    int oy = t >> 4, ox = t & 15;
    float a0 = 0.f, a1 = 0.f, a2 = 0.f, a3 = 0.f;

    for (int ci = 0; ci < 64; ++ci) {
        __syncthreads();
#pragma unroll
        for (int k = 0; k < 16; ++k) {
            int idx = k * 256 + t;
            int iy = idx >> 6, ix = idx & 63;
            xs[ix & 3][iy][ix >> 2] = x2[((size_t)(b * 64 + ci) << 12) + idx];
        }
        __syncthreads();
        const float* wp = W + (size_t)(co0 * 64 + ci) * 49;
#pragma unroll
        for (int ky = 0; ky < 7; ++ky) {
            int iy = oy * 4 - 3 + ky;
            if (iy < 0 || iy > 63) continue;
#pragma unroll
            for (int kx = 0; kx < 7; ++kx) {
                int ix = ox * 4 - 3 + kx;
                if (ix < 0 || ix > 63) continue;
                float xv = xs[ix & 3][iy][ix >> 2];
                int widx = ky * 7 + kx;
                a0 = fmaf(xv, wp[widx], a0);
                a1 = fmaf(xv, wp[64 * 49 + widx], a1);
                a2 = fmaf(xv, wp[2 * 64 * 49 + widx], a2);
                a3 = fmaf(xv, wp[3 * 64 * 49 + widx], a3);
            }
        }
    }
    size_t out = ((size_t)(b * 64 + co0) << 8) + t;
    y[out]       = a0 + bias[co0];
    y[out + 256] = a1 + bias[co0 + 1];
    y[out + 512] = a2 + bias[co0 + 2];
    y[out + 768] = a3 + bias[co0 + 3];
}

// ---------------------------------------------------------------------------
// s2[c,d] = sum_n f2[c,n]*g2[d,n]; beta2 = softmax_c(s2). grid = B, block 256.
// ---------------------------------------------------------------------------
__global__ __launch_bounds__(256) void s2_softmax_kernel(
    const float* __restrict__ f2, const float* __restrict__ g2,
    float* __restrict__ beta2)
{
    __shared__ float f2s[64][65];
    __shared__ __align__(16) float g2t[64][68];   // [n][d]
    __shared__ float s2s[64][65];
    int t = threadIdx.x;
    int b = blockIdx.x;
    int c = t & 63, dg = t >> 6, d0 = dg * 16;

    float acc[16];
#pragma unroll
    for (int k = 0; k < 16; ++k) acc[k] = 0.f;

    for (int r = 0; r < 4; ++r) {
        int nb = r * 64;
        __syncthreads();
        {
            int n = t & 63; int c0 = t >> 6;
#pragma unroll
            for (int k = 0; k < 16; ++k) {
                int cc = c0 * 16 + k;
                f2s[cc][n] = f2[((size_t)(b * 64 + cc) << 8) + nb + n];
                g2t[n][cc] = g2[((size_t)(b * 64 + cc) << 8) + nb + n];
            }
        }
        __syncthreads();
        for (int n = 0; n < 64; ++n) {
            float fv = f2s[c][n];
#pragma unroll
            for (int jj = 0; jj < 4; ++jj) {
                float4 gv = *reinterpret_cast<const float4*>(&g2t[n][d0 + jj * 4]);
                acc[jj * 4 + 0] = fmaf(fv, gv.x, acc[jj * 4 + 0]);
                acc[jj * 4 + 1] = fmaf(fv, gv.y, acc[jj * 4 + 1]);
                acc[jj * 4 + 2] = fmaf(fv, gv.z, acc[jj * 4 + 2]);
                acc[jj * 4 + 3] = fmaf(fv, gv.w, acc[jj * 4 + 3]);
            }
        }
    }
    __syncthreads();
#pragma unroll
    for (int k = 0; k < 16; ++k) s2s[c][d0 + k] = acc[k];
    __syncthreads();
    if (t < 64) {
        int d = t;
        float mx = s2s[0][d];
        for (int cc = 1; cc < 64; ++cc) mx = fmaxf(mx, s2s[cc][d]);
        float sm = 0.f;
        for (int cc = 0; cc < 64; ++cc) sm += __expf(s2s[cc][d] - mx);
        float r = 1.f / sm;
        for (int cc = 0; cc < 64; ++cc)
            beta2[((size_t)b << 12) + cc * 64 + d] = __expf(s2s[cc][d] - mx) * r;
    }
}

// ---------------------------------------------------------------------------
// out[b,d,n] = sum_c h2[b,c,n]*beta2[b,c,d] + x[b,d,n]. grid = B*64, block 256.
// ---------------------------------------------------------------------------
__global__ __launch_bounds__(256) void o2_residual_kernel(
    const float* __restrict__ h2, const float* __restrict__ beta2,
    const float* __restrict__ x, float* __restrict__ out)
{
    __shared__ __align__(16) float b2s[64][64];   // [c][d]
    __shared__ float h2s[64][65];
    int t = threadIdx.x;
    int b = blockIdx.x >> 6;
    int n0 = (blockIdx.x & 63) << 6;

    {
#pragma unroll
        for (int k = 0; k < 16; ++k) {
            int idx = k * 256 + t;
            b2s[idx >> 6][idx & 63] = beta2[((size_t)b << 12) + idx];
        }
        int n = t & 63; int c0 = t >> 6;
#pragma unroll
        for (int k = 0; k < 16; ++k) {
            int cc = c0 * 16 + k;
            h2s[cc][n] = h2[((size_t)(b * 64 + cc) << 12) + n0 + n];
        }
    }
    __syncthreads();

    int n = t & 63, dg = t >> 6, d0 = dg * 16;
    float acc[16];
#pragma unroll
    for (int k = 0; k < 16; ++k) acc[k] = 0.f;

    for (int cc = 0; cc < 64; ++cc) {
        float hv = h2s[cc][n];
#pragma unroll
        for (int jj = 0; jj < 4; ++jj) {
            float4 bv = *reinterpret_cast<const float4*>(&b2s[cc][d0 + jj * 4]);
            acc[jj * 4 + 0] = fmaf(hv, bv.x, acc[jj * 4 + 0]);
            acc[jj * 4 + 1] = fmaf(hv, bv.y, acc[jj * 4 + 1]);
            acc[jj * 4 + 2] = fmaf(hv, bv.z, acc[jj * 4 + 2]);
            acc[jj * 4 + 3] = fmaf(hv, bv.w, acc[jj * 4 + 3]);
        }
    }
#pragma unroll
    for (int k = 0; k < 16; ++k) {
        int d = d0 + k;
        size_t o = ((size_t)(b * 64 + d) << 12) + n0 + n;
        out[o] = acc[k] + x[o];
    }
}

// ---------------------------------------------------------------------------
extern "C" void kernel_launch(void* const* d_in, const int* in_sizes, int n_in,
                              void* d_out, int out_size, void* d_ws, size_t ws_size,
                              hipStream_t stream)
{
    const float* x  = (const float*)d_in[0];
    const float* w1 = (const float*)d_in[1];
    const float* b1 = (const float*)d_in[2];
    const float* w2 = (const float*)d_in[3];
    const float* b2 = (const float*)d_in[4];
    const float* w3 = (const float*)d_in[5];
    const float* b3 = (const float*)d_in[6];
    const float* w4 = (const float*)d_in[7];
    const float* b4 = (const float*)d_in[8];
    const float* w5 = (const float*)d_in[9];
    const float* b5 = (const float*)d_in[10];
    const float* w6 = (const float*)d_in[11];
    const float* b6 = (const float*)d_in[12];
    float* out = (float*)d_out;

    float* ws = (float*)d_ws;
    float* hh    = ws;                       // 4*64*4096 = 1048576
    float* x2    = hh + 1048576;             // 1048576
    float* h2    = x2 + 1048576;             // 1048576
    float* fbuf  = h2 + 1048576;             // 131072
    float* gbuf  = fbuf + 131072;            // 131072
    float* f2    = gbuf + 131072;            // 65536
    float* g2    = f2 + 65536;               // 65536
    float* beta2 = g2 + 65536;               // 16384

    // f, g, hh (1x1 convs on x)
    pw_conv_kernel<<<64, 256, 0, stream>>>(x, w1, b1, fbuf, CRR);
    pw_conv_kernel<<<64, 256, 0, stream>>>(x, w2, b2, gbuf, CRR);
    pw_conv_kernel<<<64, 256, 0, stream>>>(x, w3, b3, hh, CC);

    // fused spatial attention -> x2
    attn_kernel<<<256, 256, 0, stream>>>(fbuf, gbuf, hh, x2);

    // 7x7 stride-4 convs -> f2, g2
    conv7_kernel<<<128, 256, 0, stream>>>(x2, w4, b4, w5, b5, f2, g2);

    // h2 (1x1 conv on x2)
    pw_conv_kernel<<<64, 256, 0, stream>>>(x2, w6, b6, h2, CC);

    // s2 + softmax -> beta2
    s2_softmax_kernel<<<BB, 256, 0, stream>>>(f2, g2, beta2);

    // o2 + residual -> out
    o2_residual_kernel<<<256, 256, 0, stream>>>(h2, beta2, x, out);
}

// Round 2
// 292.963 us; speedup vs baseline: 1.9184x; 1.9184x over previous
//
#include <hip/hip_runtime.h>
#include <math.h>

#define BB 4
#define CC 64
#define CRR 8
#define NN 4096

typedef __attribute__((ext_vector_type(8))) short bf16x8;
typedef __attribute__((ext_vector_type(4))) float f32x4;

__device__ inline float bf2f(ushort u) {
    union { uint i; float f; } v; v.i = (uint)u << 16; return v.f;
}
__device__ inline ushort f2bf(float f) {
    uint u = __builtin_bit_cast(uint, f);
    u = (u + 0x7FFFu + ((u >> 16) & 1u)) >> 16;
    return (ushort)u;
}
__device__ inline uint bfpack2(float a, float b) {
    uint ua = __builtin_bit_cast(uint, a);
    uint ub = __builtin_bit_cast(uint, b);
    ua = (ua + 0x7FFFu + ((ua >> 16) & 1u)) >> 16;
    ub = (ub + 0x7FFFu + ((ub >> 16) & 1u)) & 0xFFFF0000u;
    return ua | ub;
}

// ---------------------------------------------------------------------------
// Producer: f = conv1x1(x,w1,b1), g = conv1x1(x,w2,b2), hh = conv1x1(x,w3,b3)
// Outputs: fT[b][n][8] bf16, gT[b][n][8] bf16, hhb[b][c][n] bf16.
// grid = B*64 (64 n per wg), block = 256 (4 output-groups of 20 rows).
// ---------------------------------------------------------------------------
__global__ __launch_bounds__(256) void produce_fgh(
    const float* __restrict__ x,
    const float* __restrict__ w1, const float* __restrict__ b1,
    const float* __restrict__ w2, const float* __restrict__ b2,
    const float* __restrict__ w3, const float* __restrict__ b3,
    ushort* __restrict__ fT, ushort* __restrict__ gT, ushort* __restrict__ hhb)
{
    int t = threadIdx.x;
    int b = blockIdx.x >> 6;
    int n = ((blockIdx.x & 63) << 6) + (t & 63);
    int og = __builtin_amdgcn_readfirstlane(t >> 6);  // wave-uniform

    const float* xb = x + ((size_t)b << 18) + n;
    float xv[64];
#pragma unroll
    for (int c = 0; c < 64; ++c) xv[c] = xb[(size_t)c << 12];

    if (og == 0) {
        ushort fo[8], go[8];
#pragma unroll
        for (int k = 0; k < 8; ++k) {
            float a1 = b1[k], a2 = b2[k];
#pragma unroll
            for (int c = 0; c < 64; ++c) {
                a1 = fmaf(w1[k * 64 + c], xv[c], a1);
                a2 = fmaf(w2[k * 64 + c], xv[c], a2);
            }
            fo[k] = f2bf(a1); go[k] = f2bf(a2);
        }
        uint4 fq = make_uint4((uint)fo[0] | ((uint)fo[1] << 16),
                              (uint)fo[2] | ((uint)fo[3] << 16),
                              (uint)fo[4] | ((uint)fo[5] << 16),
                              (uint)fo[6] | ((uint)fo[7] << 16));
        uint4 gq = make_uint4((uint)go[0] | ((uint)go[1] << 16),
                              (uint)go[2] | ((uint)go[3] << 16),
                              (uint)go[4] | ((uint)go[5] << 16),
                              (uint)go[6] | ((uint)go[7] << 16));
        *(uint4*)&fT[((size_t)b << 15) + (size_t)n * 8] = fq;
        *(uint4*)&gT[((size_t)b << 15) + (size_t)n * 8] = gq;
#pragma unroll
        for (int k = 0; k < 4; ++k) {
            float a = b3[k];
#pragma unroll
            for (int c = 0; c < 64; ++c) a = fmaf(w3[k * 64 + c], xv[c], a);
            hhb[((size_t)b << 18) + ((size_t)k << 12) + n] = f2bf(a);
        }
    } else {
        int c0 = og * 20 - 16;  // 4, 24, 44
#pragma unroll
        for (int k = 0; k < 20; ++k) {
            float a = b3[c0 + k];
#pragma unroll
            for (int c = 0; c < 64; ++c) a = fmaf(w3[(c0 + k) * 64 + c], xv[c], a);
            hhb[((size_t)b << 18) + ((size_t)(c0 + k) << 12) + n] = f2bf(a);
        }
    }
}

// ---------------------------------------------------------------------------
// Fused MFMA flash attention + h2 epilogue.
//   S[n,m] = sum_c f[c,n] g[c,m]; beta = softmax_n(S); x2[c,m] = sum_n hh[c,n] beta[n,m]
//   h2 = w6 * x2 + b6 (1x1 conv) fused in the epilogue.
// grid = B*64 (64 m-cols per wg), block = 256 (4 waves, 16 m each).
// ---------------------------------------------------------------------------
__global__ __launch_bounds__(256) void attn_kernel(
    const ushort* __restrict__ fT, const ushort* __restrict__ gT,
    const ushort* __restrict__ hhb, const float* __restrict__ w6,
    const float* __restrict__ b6,
    ushort* __restrict__ x2b, ushort* __restrict__ h2b)
{
    // hh fragment layout: [buf][(kk*4+g)*512 + c*8 + j]
    __shared__ ushort hhT[2][4096];   // 16 KB
    __shared__ ushort fTl[2][512];    // 2 KB   [buf][n*8 + c]
    __shared__ ushort Pst[4][1024];   // 8 KB   per-wave [m][n] XOR-swizzled

    int t = threadIdx.x;
    int l = t & 63, w = t >> 6;
    int ml = l & 15, g = l >> 4;
    int b = blockIdx.x >> 6;
    int m0 = (blockIdx.x & 63) << 6;
    int col = m0 + w * 16 + ml;

    const ushort* fTb = fT + ((size_t)b << 15);
    const ushort* gTb = gT + ((size_t)b << 15);
    const ushort* hhB = hhb + ((size_t)b << 18);

    const bf16x8 z8 = {0, 0, 0, 0, 0, 0, 0, 0};
    const f32x4 z4 = {0.f, 0.f, 0.f, 0.f};

    // B-fragment for scores: col=ml, k=8g+j (only g==0 carries c=0..7)
    bf16x8 gfrag = *(const bf16x8*)(gTb + (size_t)col * 8);
    if (g != 0) gfrag = z8;

    // staging assignment: thread t handles hh row c = t>>2, 16-n chunk p = t&3
    int sc = t >> 2, sp = t & 3;
    const ushort* hrowBase = hhB + (size_t)sc * 4096 + sp * 16;
    int hdst = ((sp >> 1) * 4 + (sp & 1) * 2) * 512 + sc * 8;

    // prologue: stage tile 0
    uint4 h0 = *(const uint4*)(hrowBase);
    uint4 h1 = *(const uint4*)(hrowBase + 8);
    uint4 fv = make_uint4(0, 0, 0, 0);
    if (t < 64) fv = *(const uint4*)(fTb + (size_t)t * 8);
    *(uint4*)&hhT[0][hdst] = h0;
    *(uint4*)&hhT[0][hdst + 512] = h1;
    if (t < 64) *(uint4*)&fTl[0][t * 8] = fv;

    f32x4 acc[4] = {z4, z4, z4, z4};
    float M = -3e38f, L = 0.f;
    int swz = (ml & 7) << 4;
    char* pbase = (char*)&Pst[w][0];
    __syncthreads();

    for (int nt = 0; nt < 64; ++nt) {
        int buf = nt & 1;
        // prefetch next tile (global -> regs), hides under compute
        if (nt < 63) {
            int n0 = (nt + 1) << 6;
            h0 = *(const uint4*)(hrowBase + n0);
            h1 = *(const uint4*)(hrowBase + n0 + 8);
            if (t < 64) fv = *(const uint4*)(fTb + (size_t)(n0 + t) * 8);
        }

        // ---- scores: 4 n-tiles of 16, K=32 (c padded 8->32) ----
        f32x4 Sv[4];
#pragma unroll
        for (int s = 0; s < 4; ++s) {
            bf16x8 af = *(const bf16x8*)&fTl[buf][(16 * s + ml) * 8];
            Sv[s] = __builtin_amdgcn_mfma_f32_16x16x32_bf16(af, gfrag, z4, 0, 0, 0);
        }

        // ---- online softmax over this 64-n block ----
        float tmax = Sv[0][0];
#pragma unroll
        for (int s = 0; s < 4; ++s)
#pragma unroll
            for (int r = 0; r < 4; ++r) tmax = fmaxf(tmax, Sv[s][r]);
        tmax = fmaxf(tmax, __shfl_xor(tmax, 16));
        tmax = fmaxf(tmax, __shfl_xor(tmax, 32));
        float Mn = fmaxf(M, tmax);
        float scl = __expf(M - Mn);
        float rsum = 0.f;
        uint plo[4], phi[4];
#pragma unroll
        for (int s = 0; s < 4; ++s) {
            float p0 = __expf(Sv[s][0] - Mn);
            float p1 = __expf(Sv[s][1] - Mn);
            float p2 = __expf(Sv[s][2] - Mn);
            float p3 = __expf(Sv[s][3] - Mn);
            rsum += (p0 + p1) + (p2 + p3);
            plo[s] = bfpack2(p0, p1);
            phi[s] = bfpack2(p2, p3);
        }
        rsum += __shfl_xor(rsum, 16);
        rsum += __shfl_xor(rsum, 32);
        L = L * scl + rsum;
        M = Mn;
#pragma unroll
        for (int ct = 0; ct < 4; ++ct) acc[ct] *= scl;

        // ---- stage P (bf16) into per-wave swizzled LDS ----
#pragma unroll
        for (int s = 0; s < 4; ++s) {
            uint off = (uint)((ml * 128 + 32 * s + 8 * g) ^ swz);
            *(uint2*)(pbase + off) = make_uint2(plo[s], phi[s]);
        }

        // ---- PV: acc[c-tile] += hh * P ----
#pragma unroll
        for (int kk = 0; kk < 2; ++kk) {
            uint off = (uint)((ml * 128 + 64 * kk + 16 * g) ^ swz);
            bf16x8 pf = *(const bf16x8*)(pbase + off);
#pragma unroll
            for (int ct = 0; ct < 4; ++ct) {
                bf16x8 hf = *(const bf16x8*)&hhT[buf][(kk * 4 + g) * 512 + (16 * ct + ml) * 8];
                acc[ct] = __builtin_amdgcn_mfma_f32_16x16x32_bf16(hf, pf, acc[ct], 0, 0, 0);
            }
        }

        // ---- write prefetched tile into other buffer ----
        if (nt < 63) {
            int nb = buf ^ 1;
            *(uint4*)&hhT[nb][hdst] = h0;
            *(uint4*)&hhT[nb][hdst + 512] = h1;
            if (t < 64) *(uint4*)&fTl[nb][t * 8] = fv;
        }
        __syncthreads();
    }

    // ---- epilogue: x2 = acc / L ; store bf16; fused h2 = w6*x2 + b6 ----
    float rL = 1.f / L;
    ushort* x2row = x2b + ((size_t)b << 18) + col;
    float xvv[4][4];
#pragma unroll
    for (int ct = 0; ct < 4; ++ct) {
#pragma unroll
        for (int r = 0; r < 4; ++r) {
            float v = acc[ct][r] * rL;
            xvv[ct][r] = v;
            int c = 16 * ct + 4 * g + r;
            x2row[(size_t)c << 12] = f2bf(v);
        }
        // stage x2 fragment into Pst (k-axis = c), same swizzle as P
        uint off = (uint)((ml * 128 + 32 * ct + 8 * g) ^ swz);
        *(uint2*)(pbase + off) = make_uint2(bfpack2(xvv[ct][0], xvv[ct][1]),
                                            bfpack2(xvv[ct][2], xvv[ct][3]));
    }

    f32x4 hacc[4] = {z4, z4, z4, z4};
#pragma unroll
    for (int kk = 0; kk < 2; ++kk) {
        uint off = (uint)((ml * 128 + 64 * kk + 16 * g) ^ swz);
        bf16x8 xf = *(const bf16x8*)(pbase + off);
#pragma unroll
        for (int dt = 0; dt < 4; ++dt) {
            const float* wr = w6 + (16 * dt + ml) * 64 + 32 * kk + 8 * g;
            float4 wa = *(const float4*)wr;
            float4 wb = *(const float4*)(wr + 4);
            bf16x8 wf;
            wf[0] = (short)f2bf(wa.x); wf[1] = (short)f2bf(wa.y);
            wf[2] = (short)f2bf(wa.z); wf[3] = (short)f2bf(wa.w);
            wf[4] = (short)f2bf(wb.x); wf[5] = (short)f2bf(wb.y);
            wf[6] = (short)f2bf(wb.z); wf[7] = (short)f2bf(wb.w);
            hacc[dt] = __builtin_amdgcn_mfma_f32_16x16x32_bf16(wf, xf, hacc[dt], 0, 0, 0);
        }
    }
    ushort* h2row = h2b + ((size_t)b << 18) + col;
#pragma unroll
    for (int dt = 0; dt < 4; ++dt)
#pragma unroll
        for (int r = 0; r < 4; ++r) {
            int d = 16 * dt + 4 * g + r;
            h2row[(size_t)d << 12] = f2bf(hacc[dt][r] + b6[d]);
        }
}

// ---------------------------------------------------------------------------
// 7x7 stride-4 pad-3 conv on bf16 x2, both w4 and w5 branches. f32 out.
// grid = B * 16 co-groups * 2 convs = 128, block = 256 (16x16 output plane).
// ---------------------------------------------------------------------------
__global__ __launch_bounds__(256) void conv7_kernel(
    const ushort* __restrict__ x2b,
    const float* __restrict__ w4, const float* __restrict__ b4,
    const float* __restrict__ w5, const float* __restrict__ b5,
    float* __restrict__ f2, float* __restrict__ g2)
{
    __shared__ float xs[4][64][17];   // input plane split by (ix mod 4)
    int t = threadIdx.x;
    int bid = blockIdx.x;
    int conv = bid & 1;
    int cog = (bid >> 1) & 15;
    int b = bid >> 5;
    int co0 = cog * 4;
    const float* W = conv ? w5 : w4;
    const float* bias = conv ? b5 : b4;
    float* y = conv ? g2 : f2;

    int oy = t >> 4, ox = t & 15;
    float a0 = 0.f, a1 = 0.f, a2 = 0.f, a3 = 0.f;

    for (int ci = 0; ci < 64; ++ci) {
        __syncthreads();
#pragma unroll
        for (int k = 0; k < 16; ++k) {
            int idx = k * 256 + t;
            int iy = idx >> 6, ix = idx & 63;
            xs[ix & 3][iy][ix >> 2] = bf2f(x2b[((size_t)(b * 64 + ci) << 12) + idx]);
        }
        __syncthreads();
        const float* wp = W + (size_t)(co0 * 64 + ci) * 49;
#pragma unroll
        for (int ky = 0; ky < 7; ++ky) {
            int iy = oy * 4 - 3 + ky;
            if (iy < 0 || iy > 63) continue;
#pragma unroll
            for (int kx = 0; kx < 7; ++kx) {
                int ix = ox * 4 - 3 + kx;
                if (ix < 0 || ix > 63) continue;
                float xv = xs[ix & 3][iy][ix >> 2];
                int widx = ky * 7 + kx;
                a0 = fmaf(xv, wp[widx], a0);
                a1 = fmaf(xv, wp[64 * 49 + widx], a1);
                a2 = fmaf(xv, wp[2 * 64 * 49 + widx], a2);
                a3 = fmaf(xv, wp[3 * 64 * 49 + widx], a3);
            }
        }
    }
    size_t out = ((size_t)(b * 64 + co0) << 8) + t;
    y[out]       = a0 + bias[co0];
    y[out + 256] = a1 + bias[co0 + 1];
    y[out + 512] = a2 + bias[co0 + 2];
    y[out + 768] = a3 + bias[co0 + 3];
}

// ---------------------------------------------------------------------------
// s2[c,d] = sum_n f2[c,n]*g2[d,n]; beta2 = softmax_c(s2). grid = B, block 256.
// ---------------------------------------------------------------------------
__global__ __launch_bounds__(256) void s2_softmax_kernel(
    const float* __restrict__ f2, const float* __restrict__ g2,
    float* __restrict__ beta2)
{
    __shared__ float f2s[64][65];
    __shared__ __align__(16) float g2t[64][68];   // [n][d]
    __shared__ float s2s[64][65];
    int t = threadIdx.x;
    int b = blockIdx.x;
    int c = t & 63, dg = t >> 6, d0 = dg * 16;

    float acc[16];
#pragma unroll
    for (int k = 0; k < 16; ++k) acc[k] = 0.f;

    for (int r = 0; r < 4; ++r) {
        int nb = r * 64;
        __syncthreads();
        {
            int n = t & 63; int c0 = t >> 6;
#pragma unroll
            for (int k = 0; k < 16; ++k) {
                int cc = c0 * 16 + k;
                f2s[cc][n] = f2[((size_t)(b * 64 + cc) << 8) + nb + n];
                g2t[n][cc] = g2[((size_t)(b * 64 + cc) << 8) + nb + n];
            }
        }
        __syncthreads();
        for (int n = 0; n < 64; ++n) {
            float fvv = f2s[c][n];
#pragma unroll
            for (int jj = 0; jj < 4; ++jj) {
                float4 gv = *reinterpret_cast<const float4*>(&g2t[n][d0 + jj * 4]);
                acc[jj * 4 + 0] = fmaf(fvv, gv.x, acc[jj * 4 + 0]);
                acc[jj * 4 + 1] = fmaf(fvv, gv.y, acc[jj * 4 + 1]);
                acc[jj * 4 + 2] = fmaf(fvv, gv.z, acc[jj * 4 + 2]);
                acc[jj * 4 + 3] = fmaf(fvv, gv.w, acc[jj * 4 + 3]);
            }
        }
    }
    __syncthreads();
#pragma unroll
    for (int k = 0; k < 16; ++k) s2s[c][d0 + k] = acc[k];
    __syncthreads();
    if (t < 64) {
        int d = t;
        float mx = s2s[0][d];
        for (int cc = 1; cc < 64; ++cc) mx = fmaxf(mx, s2s[cc][d]);
        float sm = 0.f;
        for (int cc = 0; cc < 64; ++cc) sm += __expf(s2s[cc][d] - mx);
        float r = 1.f / sm;
        for (int cc = 0; cc < 64; ++cc)
            beta2[((size_t)b << 12) + cc * 64 + d] = __expf(s2s[cc][d] - mx) * r;
    }
}

// ---------------------------------------------------------------------------
// out[b,d,n] = sum_c h2[b,c,n]*beta2[b,c,d] + x[b,d,n]. grid = B*64, block 256.
// ---------------------------------------------------------------------------
__global__ __launch_bounds__(256) void o2_residual_kernel(
    const ushort* __restrict__ h2b, const float* __restrict__ beta2,
    const float* __restrict__ x, float* __restrict__ out)
{
    __shared__ __align__(16) float b2s[64][64];   // [c][d]
    __shared__ float h2s[64][65];
    int t = threadIdx.x;
    int b = blockIdx.x >> 6;
    int n0 = (blockIdx.x & 63) << 6;

    {
#pragma unroll
        for (int k = 0; k < 16; ++k) {
            int idx = k * 256 + t;
            b2s[idx >> 6][idx & 63] = beta2[((size_t)b << 12) + idx];
        }
        int n = t & 63; int c0 = t >> 6;
#pragma unroll
        for (int k = 0; k < 16; ++k) {
            int cc = c0 * 16 + k;
            h2s[cc][n] = bf2f(h2b[((size_t)(b * 64 + cc) << 12) + n0 + n]);
        }
    }
    __syncthreads();

    int n = t & 63, dg = t >> 6, d0 = dg * 16;
    float acc[16];
#pragma unroll
    for (int k = 0; k < 16; ++k) acc[k] = 0.f;

    for (int cc = 0; cc < 64; ++cc) {
        float hv = h2s[cc][n];
#pragma unroll
        for (int jj = 0; jj < 4; ++jj) {
            float4 bv = *reinterpret_cast<const float4*>(&b2s[cc][d0 + jj * 4]);
            acc[jj * 4 + 0] = fmaf(hv, bv.x, acc[jj * 4 + 0]);
            acc[jj * 4 + 1] = fmaf(hv, bv.y, acc[jj * 4 + 1]);
            acc[jj * 4 + 2] = fmaf(hv, bv.z, acc[jj * 4 + 2]);
            acc[jj * 4 + 3] = fmaf(hv, bv.w, acc[jj * 4 + 3]);
        }
    }
#pragma unroll
    for (int k = 0; k < 16; ++k) {
        int d = d0 + k;
        size_t o = ((size_t)(b * 64 + d) << 12) + n0 + n;
        out[o] = acc[k] + x[o];
    }
}

// ---------------------------------------------------------------------------
extern "C" void kernel_launch(void* const* d_in, const int* in_sizes, int n_in,
                              void* d_out, int out_size, void* d_ws, size_t ws_size,
                              hipStream_t stream)
{
    const float* x  = (const float*)d_in[0];
    const float* w1 = (const float*)d_in[1];
    const float* b1 = (const float*)d_in[2];
    const float* w2 = (const float*)d_in[3];
    const float* b2 = (const float*)d_in[4];
    const float* w3 = (const float*)d_in[5];
    const float* b3 = (const float*)d_in[6];
    const float* w4 = (const float*)d_in[7];
    const float* b4 = (const float*)d_in[8];
    const float* w5 = (const float*)d_in[9];
    const float* b5 = (const float*)d_in[10];
    const float* w6 = (const float*)d_in[11];
    const float* b6 = (const float*)d_in[12];
    float* out = (float*)d_out;

    ushort* u = (ushort*)d_ws;
    ushort* fT  = u;                  // 4*4096*8   = 131072
    ushort* gT  = fT + 131072;        // 131072
    ushort* hhb = gT + 131072;        // 4*64*4096  = 1048576
    ushort* x2b = hhb + 1048576;      // 1048576
    ushort* h2b = x2b + 1048576;      // 1048576
    float* fr    = (float*)(h2b + 1048576);
    float* f2    = fr;                // 65536
    float* g2    = fr + 65536;        // 65536
    float* beta2 = fr + 131072;       // 16384

    produce_fgh<<<256, 256, 0, stream>>>(x, w1, b1, w2, b2, w3, b3, fT, gT, hhb);
    attn_kernel<<<256, 256, 0, stream>>>(fT, gT, hhb, w6, b6, x2b, h2b);
    conv7_kernel<<<128, 256, 0, stream>>>(x2b, w4, b4, w5, b5, f2, g2);
    s2_softmax_kernel<<<BB, 256, 0, stream>>>(f2, g2, beta2);
    o2_residual_kernel<<<256, 256, 0, stream>>>(h2b, beta2, x, out);
}

// Round 3
// 216.501 us; speedup vs baseline: 2.5960x; 1.3532x over previous
//
#include <hip/hip_runtime.h>
#include <math.h>

#define BB 4
#define CC 64
#define CRR 8
#define NN 4096

typedef __attribute__((ext_vector_type(8))) short bf16x8;
typedef __attribute__((ext_vector_type(4))) float f32x4;

__device__ inline float bf2f(ushort u) {
    union { uint i; float f; } v; v.i = (uint)u << 16; return v.f;
}
__device__ inline ushort f2bf(float f) {
    uint u = __builtin_bit_cast(uint, f);
    u = (u + 0x7FFFu + ((u >> 16) & 1u)) >> 16;
    return (ushort)u;
}
__device__ inline uint bfpack2(float a, float b) {
    uint ua = __builtin_bit_cast(uint, a);
    uint ub = __builtin_bit_cast(uint, b);
    ua = (ua + 0x7FFFu + ((ua >> 16) & 1u)) >> 16;
    ub = (ub + 0x7FFFu + ((ub >> 16) & 1u)) & 0xFFFF0000u;
    return ua | ub;
}

// x2p padded pixel-major: [b][py 70][px 70][ci 64] bf16, pad=3
#define X2P_B 313600   // 70*70*64

// ---------------------------------------------------------------------------
// Producer: f = conv1x1(x,w1,b1), g = conv1x1(x,w2,b2), hh = conv1x1(x,w3,b3)
// ---------------------------------------------------------------------------
__global__ __launch_bounds__(256) void produce_fgh(
    const float* __restrict__ x,
    const float* __restrict__ w1, const float* __restrict__ b1,
    const float* __restrict__ w2, const float* __restrict__ b2,
    const float* __restrict__ w3, const float* __restrict__ b3,
    ushort* __restrict__ fT, ushort* __restrict__ gT, ushort* __restrict__ hhb)
{
    int t = threadIdx.x;
    int b = blockIdx.x >> 6;
    int n = ((blockIdx.x & 63) << 6) + (t & 63);
    int og = __builtin_amdgcn_readfirstlane(t >> 6);  // wave-uniform

    const float* xb = x + ((size_t)b << 18) + n;
    float xv[64];
#pragma unroll
    for (int c = 0; c < 64; ++c) xv[c] = xb[(size_t)c << 12];

    if (og == 0) {
        ushort fo[8], go[8];
#pragma unroll
        for (int k = 0; k < 8; ++k) {
            float a1 = b1[k], a2 = b2[k];
#pragma unroll
            for (int c = 0; c < 64; ++c) {
                a1 = fmaf(w1[k * 64 + c], xv[c], a1);
                a2 = fmaf(w2[k * 64 + c], xv[c], a2);
            }
            fo[k] = f2bf(a1); go[k] = f2bf(a2);
        }
        uint4 fq = make_uint4((uint)fo[0] | ((uint)fo[1] << 16),
                              (uint)fo[2] | ((uint)fo[3] << 16),
                              (uint)fo[4] | ((uint)fo[5] << 16),
                              (uint)fo[6] | ((uint)fo[7] << 16));
        uint4 gq = make_uint4((uint)go[0] | ((uint)go[1] << 16),
                              (uint)go[2] | ((uint)go[3] << 16),
                              (uint)go[4] | ((uint)go[5] << 16),
                              (uint)go[6] | ((uint)go[7] << 16));
        *(uint4*)&fT[((size_t)b << 15) + (size_t)n * 8] = fq;
        *(uint4*)&gT[((size_t)b << 15) + (size_t)n * 8] = gq;
#pragma unroll
        for (int k = 0; k < 4; ++k) {
            float a = b3[k];
#pragma unroll
            for (int c = 0; c < 64; ++c) a = fmaf(w3[k * 64 + c], xv[c], a);
            hhb[((size_t)b << 18) + ((size_t)k << 12) + n] = f2bf(a);
        }
    } else {
        int c0 = og * 20 - 16;  // 4, 24, 44
#pragma unroll
        for (int k = 0; k < 20; ++k) {
            float a = b3[c0 + k];
#pragma unroll
            for (int c = 0; c < 64; ++c) a = fmaf(w3[(c0 + k) * 64 + c], xv[c], a);
            hhb[((size_t)b << 18) + ((size_t)(c0 + k) << 12) + n] = f2bf(a);
        }
    }
}

// ---------------------------------------------------------------------------
// Weight transform: Wt[conv][co][ky*7+kx][ci] (bf16) from OIHW fp32.
// grid = 128 (conv*64+co), block = 256.
// ---------------------------------------------------------------------------
__global__ __launch_bounds__(256) void wt_kernel(
    const float* __restrict__ w4, const float* __restrict__ w5,
    ushort* __restrict__ Wt)
{
    int bid = blockIdx.x;
    int conv = bid >> 6, co = bid & 63;
    const float* W = conv ? w5 : w4;
    int t = threadIdx.x;
    for (int i = t; i < 3136; i += 256) {
        int ci = i / 49, kk = i - ci * 49;
        Wt[(((size_t)(conv * 64 + co)) * 49 + kk) * 64 + ci] = f2bf(W[co * 3136 + i]);
    }
}

// ---------------------------------------------------------------------------
// Fused MFMA flash attention + h2 epilogue. x2 written to padded x2p layout.
// grid = B*64 (64 m-cols per wg), block = 256 (4 waves, 16 m each).
// ---------------------------------------------------------------------------
__global__ __launch_bounds__(256) void attn_kernel(
    const ushort* __restrict__ fT, const ushort* __restrict__ gT,
    const ushort* __restrict__ hhb, const float* __restrict__ w6,
    const float* __restrict__ b6,
    ushort* __restrict__ x2p, ushort* __restrict__ h2b)
{
    __shared__ ushort hhT[2][4096];   // 16 KB
    __shared__ ushort fTl[2][512];    // 2 KB
    __shared__ ushort Pst[4][1024];   // 8 KB per-wave swizzled

    int t = threadIdx.x;
    int l = t & 63, w = t >> 6;
    int ml = l & 15, g = l >> 4;
    int b = blockIdx.x >> 6;
    int m0 = (blockIdx.x & 63) << 6;
    int col = m0 + w * 16 + ml;

    const ushort* fTb = fT + ((size_t)b << 15);
    const ushort* gTb = gT + ((size_t)b << 15);
    const ushort* hhB = hhb + ((size_t)b << 18);

    const bf16x8 z8 = {0, 0, 0, 0, 0, 0, 0, 0};
    const f32x4 z4 = {0.f, 0.f, 0.f, 0.f};

    bf16x8 gfrag = *(const bf16x8*)(gTb + (size_t)col * 8);
    if (g != 0) gfrag = z8;

    int sc = t >> 2, sp = t & 3;
    const ushort* hrowBase = hhB + (size_t)sc * 4096 + sp * 16;
    int hdst = ((sp >> 1) * 4 + (sp & 1) * 2) * 512 + sc * 8;

    uint4 h0 = *(const uint4*)(hrowBase);
    uint4 h1 = *(const uint4*)(hrowBase + 8);
    uint4 fv = make_uint4(0, 0, 0, 0);
    if (t < 64) fv = *(const uint4*)(fTb + (size_t)t * 8);
    *(uint4*)&hhT[0][hdst] = h0;
    *(uint4*)&hhT[0][hdst + 512] = h1;
    if (t < 64) *(uint4*)&fTl[0][t * 8] = fv;

    f32x4 acc[4] = {z4, z4, z4, z4};
    float M = -3e38f, L = 0.f;
    int swz = (ml & 7) << 4;
    char* pbase = (char*)&Pst[w][0];
    __syncthreads();

    for (int nt = 0; nt < 64; ++nt) {
        int buf = nt & 1;
        if (nt < 63) {
            int n0 = (nt + 1) << 6;
            h0 = *(const uint4*)(hrowBase + n0);
            h1 = *(const uint4*)(hrowBase + n0 + 8);
            if (t < 64) fv = *(const uint4*)(fTb + (size_t)(n0 + t) * 8);
        }

        f32x4 Sv[4];
#pragma unroll
        for (int s = 0; s < 4; ++s) {
            bf16x8 af = *(const bf16x8*)&fTl[buf][(16 * s + ml) * 8];
            Sv[s] = __builtin_amdgcn_mfma_f32_16x16x32_bf16(af, gfrag, z4, 0, 0, 0);
        }

        float tmax = Sv[0][0];
#pragma unroll
        for (int s = 0; s < 4; ++s)
#pragma unroll
            for (int r = 0; r < 4; ++r) tmax = fmaxf(tmax, Sv[s][r]);
        tmax = fmaxf(tmax, __shfl_xor(tmax, 16));
        tmax = fmaxf(tmax, __shfl_xor(tmax, 32));
        float Mn = fmaxf(M, tmax);
        float scl = __expf(M - Mn);
        float rsum = 0.f;
        uint plo[4], phi[4];
#pragma unroll
        for (int s = 0; s < 4; ++s) {
            float p0 = __expf(Sv[s][0] - Mn);
            float p1 = __expf(Sv[s][1] - Mn);
            float p2 = __expf(Sv[s][2] - Mn);
            float p3 = __expf(Sv[s][3] - Mn);
            rsum += (p0 + p1) + (p2 + p3);
            plo[s] = bfpack2(p0, p1);
            phi[s] = bfpack2(p2, p3);
        }
        rsum += __shfl_xor(rsum, 16);
        rsum += __shfl_xor(rsum, 32);
        L = L * scl + rsum;
        M = Mn;
#pragma unroll
        for (int ct = 0; ct < 4; ++ct) acc[ct] *= scl;

#pragma unroll
        for (int s = 0; s < 4; ++s) {
            uint off = (uint)((ml * 128 + 32 * s + 8 * g) ^ swz);
            *(uint2*)(pbase + off) = make_uint2(plo[s], phi[s]);
        }

#pragma unroll
        for (int kk = 0; kk < 2; ++kk) {
            uint off = (uint)((ml * 128 + 64 * kk + 16 * g) ^ swz);
            bf16x8 pf = *(const bf16x8*)(pbase + off);
#pragma unroll
            for (int ct = 0; ct < 4; ++ct) {
                bf16x8 hf = *(const bf16x8*)&hhT[buf][(kk * 4 + g) * 512 + (16 * ct + ml) * 8];
                acc[ct] = __builtin_amdgcn_mfma_f32_16x16x32_bf16(hf, pf, acc[ct], 0, 0, 0);
            }
        }

        if (nt < 63) {
            int nb = buf ^ 1;
            *(uint4*)&hhT[nb][hdst] = h0;
            *(uint4*)&hhT[nb][hdst + 512] = h1;
            if (t < 64) *(uint4*)&fTl[nb][t * 8] = fv;
        }
        __syncthreads();
    }

    // ---- epilogue: x2 = acc / L -> x2p (padded, pixel-major); fused h2 ----
    float rL = 1.f / L;
    ushort* xprow = x2p + (size_t)b * X2P_B
                  + ((size_t)((col >> 6) + 3) * 70 + (col & 63) + 3) * 64;
    float xvv[4][4];
#pragma unroll
    for (int ct = 0; ct < 4; ++ct) {
#pragma unroll
        for (int r = 0; r < 4; ++r) xvv[ct][r] = acc[ct][r] * rL;
        *(uint2*)(xprow + 16 * ct + 4 * g) =
            make_uint2(bfpack2(xvv[ct][0], xvv[ct][1]),
                       bfpack2(xvv[ct][2], xvv[ct][3]));
        uint off = (uint)((ml * 128 + 32 * ct + 8 * g) ^ swz);
        *(uint2*)(pbase + off) = make_uint2(bfpack2(xvv[ct][0], xvv[ct][1]),
                                            bfpack2(xvv[ct][2], xvv[ct][3]));
    }

    f32x4 hacc[4] = {z4, z4, z4, z4};
#pragma unroll
    for (int kk = 0; kk < 2; ++kk) {
        uint off = (uint)((ml * 128 + 64 * kk + 16 * g) ^ swz);
        bf16x8 xf = *(const bf16x8*)(pbase + off);
#pragma unroll
        for (int dt = 0; dt < 4; ++dt) {
            const float* wr = w6 + (16 * dt + ml) * 64 + 32 * kk + 8 * g;
            float4 wa = *(const float4*)wr;
            float4 wb = *(const float4*)(wr + 4);
            bf16x8 wf;
            wf[0] = (short)f2bf(wa.x); wf[1] = (short)f2bf(wa.y);
            wf[2] = (short)f2bf(wa.z); wf[3] = (short)f2bf(wa.w);
            wf[4] = (short)f2bf(wb.x); wf[5] = (short)f2bf(wb.y);
            wf[6] = (short)f2bf(wb.z); wf[7] = (short)f2bf(wb.w);
            hacc[dt] = __builtin_amdgcn_mfma_f32_16x16x32_bf16(wf, xf, hacc[dt], 0, 0, 0);
        }
    }
    ushort* h2row = h2b + ((size_t)b << 18) + col;
#pragma unroll
    for (int dt = 0; dt < 4; ++dt)
#pragma unroll
        for (int r = 0; r < 4; ++r) {
            int d = 16 * dt + 4 * g + r;
            h2row[(size_t)d << 12] = f2bf(hacc[dt][r] + b6[d]);
        }
}

// ---------------------------------------------------------------------------
// 7x7 stride-4 pad-3 conv as MFMA implicit GEMM. No LDS, no barriers.
// grid = 32 (b*8 + conv*4 + oq), block = 256 (4 waves x 16 opix).
// Y[co,opix] = sum_{ky,kx,ci} Wt[conv][co][kk][ci] * x2p[b][oy*4+ky][ox*4+kx][ci]
// ---------------------------------------------------------------------------
__global__ __launch_bounds__(256) void conv7_mfma_kernel(
    const ushort* __restrict__ x2p, const ushort* __restrict__ Wt,
    const float* __restrict__ b4, const float* __restrict__ b5,
    float* __restrict__ f2, float* __restrict__ g2)
{
    int t = threadIdx.x;
    int l = t & 63, w = t >> 6;
    int ml = l & 15, g = l >> 4;
    int bid = blockIdx.x;
    int oq = bid & 3, conv = (bid >> 2) & 1, b = bid >> 3;
    int opix = oq * 64 + w * 16 + ml;
    int oy = opix >> 4, ox = opix & 15;

    const ushort* xb = x2p + (size_t)b * X2P_B + (size_t)(oy * 4 * 70 + ox * 4) * 64 + g * 8;
    const ushort* wb = Wt + (size_t)conv * 200704 + g * 8;   // + co*49*64 + kk*64
    const float* bias = conv ? b5 : b4;
    float* y = conv ? g2 : f2;

    const f32x4 z4 = {0.f, 0.f, 0.f, 0.f};
    f32x4 acc[4] = {z4, z4, z4, z4};

#pragma unroll 1
    for (int ky = 0; ky < 7; ++ky) {
#pragma unroll
        for (int kx = 0; kx < 7; ++kx) {
            int kk = ky * 7 + kx;
            const ushort* xrow = xb + (size_t)(ky * 70 + kx) * 64;
#pragma unroll
            for (int ci0 = 0; ci0 < 64; ci0 += 32) {
                bf16x8 bv = *(const bf16x8*)(xrow + ci0);
#pragma unroll
                for (int ct = 0; ct < 4; ++ct) {
                    bf16x8 av = *(const bf16x8*)(wb + (size_t)((16 * ct + ml) * 49 + kk) * 64 + ci0);
                    acc[ct] = __builtin_amdgcn_mfma_f32_16x16x32_bf16(av, bv, acc[ct], 0, 0, 0);
                }
            }
        }
    }

#pragma unroll
    for (int ct = 0; ct < 4; ++ct)
#pragma unroll
        for (int r = 0; r < 4; ++r) {
            int co = 16 * ct + 4 * g + r;
            y[((size_t)(b * 64 + co) << 8) + opix] = acc[ct][r] + bias[co];
        }
}

// ---------------------------------------------------------------------------
// s2[c,d] = sum_n f2[c,n]*g2[d,n]; beta2 = softmax_c(s2). grid = B, block 256.
// ---------------------------------------------------------------------------
__global__ __launch_bounds__(256) void s2_softmax_kernel(
    const float* __restrict__ f2, const float* __restrict__ g2,
    float* __restrict__ beta2)
{
    __shared__ float f2s[64][65];
    __shared__ __align__(16) float g2t[64][68];   // [n][d]
    __shared__ float s2s[64][65];
    int t = threadIdx.x;
    int b = blockIdx.x;
    int c = t & 63, dg = t >> 6, d0 = dg * 16;

    float acc[16];
#pragma unroll
    for (int k = 0; k < 16; ++k) acc[k] = 0.f;

    for (int r = 0; r < 4; ++r) {
        int nb = r * 64;
        __syncthreads();
        {
            int n = t & 63; int c0 = t >> 6;
#pragma unroll
            for (int k = 0; k < 16; ++k) {
                int cc = c0 * 16 + k;
                f2s[cc][n] = f2[((size_t)(b * 64 + cc) << 8) + nb + n];
                g2t[n][cc] = g2[((size_t)(b * 64 + cc) << 8) + nb + n];
            }
        }
        __syncthreads();
        for (int n = 0; n < 64; ++n) {
            float fvv = f2s[c][n];
#pragma unroll
            for (int jj = 0; jj < 4; ++jj) {
                float4 gv = *reinterpret_cast<const float4*>(&g2t[n][d0 + jj * 4]);
                acc[jj * 4 + 0] = fmaf(fvv, gv.x, acc[jj * 4 + 0]);
                acc[jj * 4 + 1] = fmaf(fvv, gv.y, acc[jj * 4 + 1]);
                acc[jj * 4 + 2] = fmaf(fvv, gv.z, acc[jj * 4 + 2]);
                acc[jj * 4 + 3] = fmaf(fvv, gv.w, acc[jj * 4 + 3]);
            }
        }
    }
    __syncthreads();
#pragma unroll
    for (int k = 0; k < 16; ++k) s2s[c][d0 + k] = acc[k];
    __syncthreads();
    if (t < 64) {
        int d = t;
        float mx = s2s[0][d];
        for (int cc = 1; cc < 64; ++cc) mx = fmaxf(mx, s2s[cc][d]);
        float sm = 0.f;
        for (int cc = 0; cc < 64; ++cc) sm += __expf(s2s[cc][d] - mx);
        float r = 1.f / sm;
        for (int cc = 0; cc < 64; ++cc)
            beta2[((size_t)b << 12) + cc * 64 + d] = __expf(s2s[cc][d] - mx) * r;
    }
}

// ---------------------------------------------------------------------------
// out[b,d,n] = sum_c h2[b,c,n]*beta2[b,c,d] + x[b,d,n]. grid = B*64, block 256.
// ---------------------------------------------------------------------------
__global__ __launch_bounds__(256) void o2_residual_kernel(
    const ushort* __restrict__ h2b, const float* __restrict__ beta2,
    const float* __restrict__ x, float* __restrict__ out)
{
    __shared__ __align__(16) float b2s[64][64];   // [c][d]
    __shared__ float h2s[64][65];
    int t = threadIdx.x;
    int b = blockIdx.x >> 6;
    int n0 = (blockIdx.x & 63) << 6;

    {
#pragma unroll
        for (int k = 0; k < 16; ++k) {
            int idx = k * 256 + t;
            b2s[idx >> 6][idx & 63] = beta2[((size_t)b << 12) + idx];
        }
        int n = t & 63; int c0 = t >> 6;
#pragma unroll
        for (int k = 0; k < 16; ++k) {
            int cc = c0 * 16 + k;
            h2s[cc][n] = bf2f(h2b[((size_t)(b * 64 + cc) << 12) + n0 + n]);
        }
    }
    __syncthreads();

    int n = t & 63, dg = t >> 6, d0 = dg * 16;
    float acc[16];
#pragma unroll
    for (int k = 0; k < 16; ++k) acc[k] = 0.f;

    for (int cc = 0; cc < 64; ++cc) {
        float hv = h2s[cc][n];
#pragma unroll
        for (int jj = 0; jj < 4; ++jj) {
            float4 bv = *reinterpret_cast<const float4*>(&b2s[cc][d0 + jj * 4]);
            acc[jj * 4 + 0] = fmaf(hv, bv.x, acc[jj * 4 + 0]);
            acc[jj * 4 + 1] = fmaf(hv, bv.y, acc[jj * 4 + 1]);
            acc[jj * 4 + 2] = fmaf(hv, bv.z, acc[jj * 4 + 2]);
            acc[jj * 4 + 3] = fmaf(hv, bv.w, acc[jj * 4 + 3]);
        }
    }
#pragma unroll
    for (int k = 0; k < 16; ++k) {
        int d = d0 + k;
        size_t o = ((size_t)(b * 64 + d) << 12) + n0 + n;
        out[o] = acc[k] + x[o];
    }
}

// ---------------------------------------------------------------------------
extern "C" void kernel_launch(void* const* d_in, const int* in_sizes, int n_in,
                              void* d_out, int out_size, void* d_ws, size_t ws_size,
                              hipStream_t stream)
{
    const float* x  = (const float*)d_in[0];
    const float* w1 = (const float*)d_in[1];
    const float* b1 = (const float*)d_in[2];
    const float* w2 = (const float*)d_in[3];
    const float* b2 = (const float*)d_in[4];
    const float* w3 = (const float*)d_in[5];
    const float* b3 = (const float*)d_in[6];
    const float* w4 = (const float*)d_in[7];
    const float* b4 = (const float*)d_in[8];
    const float* w5 = (const float*)d_in[9];
    const float* b5 = (const float*)d_in[10];
    const float* w6 = (const float*)d_in[11];
    const float* b6 = (const float*)d_in[12];
    float* out = (float*)d_out;

    ushort* u = (ushort*)d_ws;
    ushort* fT  = u;                  // 131072 elems
    ushort* gT  = fT + 131072;        // 131072
    ushort* hhb = gT + 131072;        // 1048576
    ushort* x2p = hhb + 1048576;      // 1254400 (4*70*70*64), padded
    ushort* h2b = x2p + 1254400;      // 1048576
    ushort* Wt  = h2b + 1048576;      // 401408 (2*64*49*64)
    float* fr    = (float*)(Wt + 401408);
    float* f2    = fr;                // 65536
    float* g2    = fr + 65536;        // 65536
    float* beta2 = fr + 131072;       // 16384

    produce_fgh<<<256, 256, 0, stream>>>(x, w1, b1, w2, b2, w3, b3, fT, gT, hhb);
    wt_kernel<<<128, 256, 0, stream>>>(w4, w5, Wt);
    hipMemsetAsync(x2p, 0, (size_t)4 * X2P_B * sizeof(ushort), stream);
    attn_kernel<<<256, 256, 0, stream>>>(fT, gT, hhb, w6, b6, x2p, h2b);
    conv7_mfma_kernel<<<32, 256, 0, stream>>>(x2p, Wt, b4, b5, f2, g2);
    s2_softmax_kernel<<<BB, 256, 0, stream>>>(f2, g2, beta2);
    o2_residual_kernel<<<256, 256, 0, stream>>>(h2b, beta2, x, out);
}

// Round 4
// 138.337 us; speedup vs baseline: 4.0628x; 1.5650x over previous
//
#include <hip/hip_runtime.h>
#include <math.h>

#define BB 4
#define CC 64
#define CRR 8
#define NN 4096

typedef __attribute__((ext_vector_type(8))) short bf16x8;
typedef __attribute__((ext_vector_type(4))) float f32x4;

__device__ inline float bf2f(ushort u) {
    union { uint i; float f; } v; v.i = (uint)u << 16; return v.f;
}
__device__ inline ushort f2bf(float f) {
    uint u = __builtin_bit_cast(uint, f);
    u = (u + 0x7FFFu + ((u >> 16) & 1u)) >> 16;
    return (ushort)u;
}
__device__ inline uint bfpack2(float a, float b) {
    uint ua = __builtin_bit_cast(uint, a);
    uint ub = __builtin_bit_cast(uint, b);
    ua = (ua + 0x7FFFu + ((ua >> 16) & 1u)) >> 16;
    ub = (ub + 0x7FFFu + ((ub >> 16) & 1u)) & 0xFFFF0000u;
    return ua | ub;
}

// x2p padded pixel-major: [b][py 70][px 70][ci 64] bf16, pad=3
#define X2P_B 313600   // 70*70*64

// ---------------------------------------------------------------------------
// Producer: f = conv1x1(x,w1,b1), g = conv1x1(x,w2,b2), hh = conv1x1(x,w3,b3)
// ---------------------------------------------------------------------------
__global__ __launch_bounds__(256) void produce_fgh(
    const float* __restrict__ x,
    const float* __restrict__ w1, const float* __restrict__ b1,
    const float* __restrict__ w2, const float* __restrict__ b2,
    const float* __restrict__ w3, const float* __restrict__ b3,
    ushort* __restrict__ fT, ushort* __restrict__ gT, ushort* __restrict__ hhb)
{
    int t = threadIdx.x;
    int b = blockIdx.x >> 6;
    int n = ((blockIdx.x & 63) << 6) + (t & 63);
    int og = __builtin_amdgcn_readfirstlane(t >> 6);  // wave-uniform

    const float* xb = x + ((size_t)b << 18) + n;
    float xv[64];
#pragma unroll
    for (int c = 0; c < 64; ++c) xv[c] = xb[(size_t)c << 12];

    if (og == 0) {
        ushort fo[8], go[8];
#pragma unroll
        for (int k = 0; k < 8; ++k) {
            float a1 = b1[k], a2 = b2[k];
#pragma unroll
            for (int c = 0; c < 64; ++c) {
                a1 = fmaf(w1[k * 64 + c], xv[c], a1);
                a2 = fmaf(w2[k * 64 + c], xv[c], a2);
            }
            fo[k] = f2bf(a1); go[k] = f2bf(a2);
        }
        uint4 fq = make_uint4((uint)fo[0] | ((uint)fo[1] << 16),
                              (uint)fo[2] | ((uint)fo[3] << 16),
                              (uint)fo[4] | ((uint)fo[5] << 16),
                              (uint)fo[6] | ((uint)fo[7] << 16));
        uint4 gq = make_uint4((uint)go[0] | ((uint)go[1] << 16),
                              (uint)go[2] | ((uint)go[3] << 16),
                              (uint)go[4] | ((uint)go[5] << 16),
                              (uint)go[6] | ((uint)go[7] << 16));
        *(uint4*)&fT[((size_t)b << 15) + (size_t)n * 8] = fq;
        *(uint4*)&gT[((size_t)b << 15) + (size_t)n * 8] = gq;
#pragma unroll
        for (int k = 0; k < 4; ++k) {
            float a = b3[k];
#pragma unroll
            for (int c = 0; c < 64; ++c) a = fmaf(w3[k * 64 + c], xv[c], a);
            hhb[((size_t)b << 18) + ((size_t)k << 12) + n] = f2bf(a);
        }
    } else {
        int c0 = og * 20 - 16;  // 4, 24, 44
#pragma unroll
        for (int k = 0; k < 20; ++k) {
            float a = b3[c0 + k];
#pragma unroll
            for (int c = 0; c < 64; ++c) a = fmaf(w3[(c0 + k) * 64 + c], xv[c], a);
            hhb[((size_t)b << 18) + ((size_t)(c0 + k) << 12) + n] = f2bf(a);
        }
    }
}

// ---------------------------------------------------------------------------
// Weight transform: Wt[conv][co][ky*7+kx][ci] (bf16) from OIHW fp32.
// ---------------------------------------------------------------------------
__global__ __launch_bounds__(256) void wt_kernel(
    const float* __restrict__ w4, const float* __restrict__ w5,
    ushort* __restrict__ Wt)
{
    int bid = blockIdx.x;
    int conv = bid >> 6, co = bid & 63;
    const float* W = conv ? w5 : w4;
    int t = threadIdx.x;
    for (int i = t; i < 3136; i += 256) {
        int ci = i / 49, kk = i - ci * 49;
        Wt[(((size_t)(conv * 64 + co)) * 49 + kk) * 64 + ci] = f2bf(W[co * 3136 + i]);
    }
}

// ---------------------------------------------------------------------------
// Fused MFMA flash attention + h2 epilogue. x2 written to padded x2p layout.
// grid = B*64 (64 m-cols per wg), block = 256 (4 waves, 16 m each).
// ---------------------------------------------------------------------------
__global__ __launch_bounds__(256) void attn_kernel(
    const ushort* __restrict__ fT, const ushort* __restrict__ gT,
    const ushort* __restrict__ hhb, const float* __restrict__ w6,
    const float* __restrict__ b6,
    ushort* __restrict__ x2p, ushort* __restrict__ h2b)
{
    __shared__ ushort hhT[2][4096];   // 16 KB
    __shared__ ushort fTl[2][512];    // 2 KB
    __shared__ ushort Pst[4][1024];   // 8 KB per-wave swizzled

    int t = threadIdx.x;
    int l = t & 63, w = t >> 6;
    int ml = l & 15, g = l >> 4;
    int b = blockIdx.x >> 6;
    int m0 = (blockIdx.x & 63) << 6;
    int col = m0 + w * 16 + ml;

    const ushort* fTb = fT + ((size_t)b << 15);
    const ushort* gTb = gT + ((size_t)b << 15);
    const ushort* hhB = hhb + ((size_t)b << 18);

    const bf16x8 z8 = {0, 0, 0, 0, 0, 0, 0, 0};
    const f32x4 z4 = {0.f, 0.f, 0.f, 0.f};

    bf16x8 gfrag = *(const bf16x8*)(gTb + (size_t)col * 8);
    if (g != 0) gfrag = z8;

    int sc = t >> 2, sp = t & 3;
    const ushort* hrowBase = hhB + (size_t)sc * 4096 + sp * 16;
    int hdst = ((sp >> 1) * 4 + (sp & 1) * 2) * 512 + sc * 8;

    uint4 h0 = *(const uint4*)(hrowBase);
    uint4 h1 = *(const uint4*)(hrowBase + 8);
    uint4 fv = make_uint4(0, 0, 0, 0);
    if (t < 64) fv = *(const uint4*)(fTb + (size_t)t * 8);
    *(uint4*)&hhT[0][hdst] = h0;
    *(uint4*)&hhT[0][hdst + 512] = h1;
    if (t < 64) *(uint4*)&fTl[0][t * 8] = fv;

    f32x4 acc[4] = {z4, z4, z4, z4};
    float M = -3e38f, L = 0.f;
    int swz = (ml & 7) << 4;
    char* pbase = (char*)&Pst[w][0];
    __syncthreads();

    for (int nt = 0; nt < 64; ++nt) {
        int buf = nt & 1;
        if (nt < 63) {
            int n0 = (nt + 1) << 6;
            h0 = *(const uint4*)(hrowBase + n0);
            h1 = *(const uint4*)(hrowBase + n0 + 8);
            if (t < 64) fv = *(const uint4*)(fTb + (size_t)(n0 + t) * 8);
        }

        f32x4 Sv[4];
#pragma unroll
        for (int s = 0; s < 4; ++s) {
            bf16x8 af = *(const bf16x8*)&fTl[buf][(16 * s + ml) * 8];
            Sv[s] = __builtin_amdgcn_mfma_f32_16x16x32_bf16(af, gfrag, z4, 0, 0, 0);
        }

        float tmax = Sv[0][0];
#pragma unroll
        for (int s = 0; s < 4; ++s)
#pragma unroll
            for (int r = 0; r < 4; ++r) tmax = fmaxf(tmax, Sv[s][r]);
        tmax = fmaxf(tmax, __shfl_xor(tmax, 16));
        tmax = fmaxf(tmax, __shfl_xor(tmax, 32));
        float Mn = fmaxf(M, tmax);
        float scl = __expf(M - Mn);
        float rsum = 0.f;
        uint plo[4], phi[4];
#pragma unroll
        for (int s = 0; s < 4; ++s) {
            float p0 = __expf(Sv[s][0] - Mn);
            float p1 = __expf(Sv[s][1] - Mn);
            float p2 = __expf(Sv[s][2] - Mn);
            float p3 = __expf(Sv[s][3] - Mn);
            rsum += (p0 + p1) + (p2 + p3);
            plo[s] = bfpack2(p0, p1);
            phi[s] = bfpack2(p2, p3);
        }
        rsum += __shfl_xor(rsum, 16);
        rsum += __shfl_xor(rsum, 32);
        L = L * scl + rsum;
        M = Mn;
#pragma unroll
        for (int ct = 0; ct < 4; ++ct) acc[ct] *= scl;

#pragma unroll
        for (int s = 0; s < 4; ++s) {
            uint off = (uint)((ml * 128 + 32 * s + 8 * g) ^ swz);
            *(uint2*)(pbase + off) = make_uint2(plo[s], phi[s]);
        }

#pragma unroll
        for (int kk = 0; kk < 2; ++kk) {
            uint off = (uint)((ml * 128 + 64 * kk + 16 * g) ^ swz);
            bf16x8 pf = *(const bf16x8*)(pbase + off);
#pragma unroll
            for (int ct = 0; ct < 4; ++ct) {
                bf16x8 hf = *(const bf16x8*)&hhT[buf][(kk * 4 + g) * 512 + (16 * ct + ml) * 8];
                acc[ct] = __builtin_amdgcn_mfma_f32_16x16x32_bf16(hf, pf, acc[ct], 0, 0, 0);
            }
        }

        if (nt < 63) {
            int nb = buf ^ 1;
            *(uint4*)&hhT[nb][hdst] = h0;
            *(uint4*)&hhT[nb][hdst + 512] = h1;
            if (t < 64) *(uint4*)&fTl[nb][t * 8] = fv;
        }
        __syncthreads();
    }

    // ---- epilogue: x2 = acc / L -> x2p (padded, pixel-major); fused h2 ----
    float rL = 1.f / L;
    ushort* xprow = x2p + (size_t)b * X2P_B
                  + ((size_t)((col >> 6) + 3) * 70 + (col & 63) + 3) * 64;
    float xvv[4][4];
#pragma unroll
    for (int ct = 0; ct < 4; ++ct) {
#pragma unroll
        for (int r = 0; r < 4; ++r) xvv[ct][r] = acc[ct][r] * rL;
        *(uint2*)(xprow + 16 * ct + 4 * g) =
            make_uint2(bfpack2(xvv[ct][0], xvv[ct][1]),
                       bfpack2(xvv[ct][2], xvv[ct][3]));
        uint off = (uint)((ml * 128 + 32 * ct + 8 * g) ^ swz);
        *(uint2*)(pbase + off) = make_uint2(bfpack2(xvv[ct][0], xvv[ct][1]),
                                            bfpack2(xvv[ct][2], xvv[ct][3]));
    }

    f32x4 hacc[4] = {z4, z4, z4, z4};
#pragma unroll
    for (int kk = 0; kk < 2; ++kk) {
        uint off = (uint)((ml * 128 + 64 * kk + 16 * g) ^ swz);
        bf16x8 xf = *(const bf16x8*)(pbase + off);
#pragma unroll
        for (int dt = 0; dt < 4; ++dt) {
            const float* wr = w6 + (16 * dt + ml) * 64 + 32 * kk + 8 * g;
            float4 wa = *(const float4*)wr;
            float4 wb = *(const float4*)(wr + 4);
            bf16x8 wf;
            wf[0] = (short)f2bf(wa.x); wf[1] = (short)f2bf(wa.y);
            wf[2] = (short)f2bf(wa.z); wf[3] = (short)f2bf(wa.w);
            wf[4] = (short)f2bf(wb.x); wf[5] = (short)f2bf(wb.y);
            wf[6] = (short)f2bf(wb.z); wf[7] = (short)f2bf(wb.w);
            hacc[dt] = __builtin_amdgcn_mfma_f32_16x16x32_bf16(wf, xf, hacc[dt], 0, 0, 0);
        }
    }
    ushort* h2row = h2b + ((size_t)b << 18) + col;
#pragma unroll
    for (int dt = 0; dt < 4; ++dt)
#pragma unroll
        for (int r = 0; r < 4; ++r) {
            int d = 16 * dt + 4 * g + r;
            h2row[(size_t)d << 12] = f2bf(hacc[dt][r] + b6[d]);
        }
}

// ---------------------------------------------------------------------------
// 7x7 stride-4 conv, ky-split implicit GEMM. grid = 224 wgs (896 waves),
// wave = (b,conv,ky,co-tile,opix-quarter): 14 K-steps, 56 MFMA.
// part[ky][b*2+conv][co][opix] fp32 partial sums.
// ---------------------------------------------------------------------------
__global__ __launch_bounds__(256) void conv7_split_kernel(
    const ushort* __restrict__ x2p, const ushort* __restrict__ Wt,
    float* __restrict__ part)
{
    int t = threadIdx.x;
    int l = t & 63, w = t >> 6;
    int ml = l & 15, g = l >> 4;
    int W = blockIdx.x * 4 + w;           // 0..895
    int og = W & 3;                       // opix quarter (4 tiles of 16)
    int ct = (W >> 2) & 3;                // co tile
    int rest = W >> 4;                    // 0..55
    int ky = rest % 7;
    int bc = rest / 7;                    // b*2+conv
    int conv = bc & 1, b = bc >> 1;

    int co0 = ct * 16;
    const ushort* wb = Wt + (size_t)conv * 200704
                     + (size_t)(co0 + ml) * 3136 + (size_t)(ky * 7) * 64 + g * 8;
    const ushort* xbase = x2p + (size_t)b * X2P_B + g * 8;

    int pixoff[4];
#pragma unroll
    for (int s = 0; s < 4; ++s) {
        int opix = og * 64 + s * 16 + ml;
        int oy = opix >> 4, ox = opix & 15;
        pixoff[s] = ((oy * 4 + ky) * 70 + ox * 4) * 64;
    }

    const f32x4 z4 = {0.f, 0.f, 0.f, 0.f};
    f32x4 acc[4] = {z4, z4, z4, z4};

#pragma unroll
    for (int kx = 0; kx < 7; ++kx) {
#pragma unroll
        for (int ci0 = 0; ci0 < 64; ci0 += 32) {
            bf16x8 av = *(const bf16x8*)(wb + kx * 64 + ci0);
#pragma unroll
            for (int s = 0; s < 4; ++s) {
                bf16x8 bv = *(const bf16x8*)(xbase + pixoff[s] + kx * 64 + ci0);
                acc[s] = __builtin_amdgcn_mfma_f32_16x16x32_bf16(av, bv, acc[s], 0, 0, 0);
            }
        }
    }

    float* pb = part + (size_t)(ky * 8 + bc) * 16384;
#pragma unroll
    for (int s = 0; s < 4; ++s) {
        int opix = og * 64 + s * 16 + ml;
#pragma unroll
        for (int r = 0; r < 4; ++r) {
            int co = co0 + 4 * g + r;
            pb[co * 256 + opix] = acc[s][r];
        }
    }
}

// ---------------------------------------------------------------------------
// Reduce 7 ky-partials + bias -> f2/g2. grid = 128, block = 256, float4/thr.
// ---------------------------------------------------------------------------
__global__ __launch_bounds__(256) void conv7_reduce_kernel(
    const float* __restrict__ part, const float* __restrict__ b4,
    const float* __restrict__ b5, float* __restrict__ f2, float* __restrict__ g2)
{
    int idx = (blockIdx.x * 256 + threadIdx.x) * 4;   // over 131072 floats
    int bc = idx >> 14;
    int co = (idx >> 8) & 63;
    int conv = bc & 1, b = bc >> 1;
    int sub = idx & 16383;
    float4 s = make_float4(0.f, 0.f, 0.f, 0.f);
#pragma unroll
    for (int ky = 0; ky < 7; ++ky) {
        float4 v = *(const float4*)&part[(size_t)(ky * 8 + bc) * 16384 + sub];
        s.x += v.x; s.y += v.y; s.z += v.z; s.w += v.w;
    }
    float bias = (conv ? b5 : b4)[co];
    s.x += bias; s.y += bias; s.z += bias; s.w += bias;
    float* y = conv ? g2 : f2;
    *(float4*)&y[(size_t)b * 16384 + sub] = s;
}

// ---------------------------------------------------------------------------
// s2[c,d] = sum_n f2[c,n]*g2[d,n]; beta2 = softmax_c(s2). grid = B, block 256.
// ---------------------------------------------------------------------------
__global__ __launch_bounds__(256) void s2_softmax_kernel(
    const float* __restrict__ f2, const float* __restrict__ g2,
    float* __restrict__ beta2)
{
    __shared__ float f2s[64][65];
    __shared__ __align__(16) float g2t[64][68];   // [n][d]
    __shared__ float s2s[64][65];
    int t = threadIdx.x;
    int b = blockIdx.x;
    int c = t & 63, dg = t >> 6, d0 = dg * 16;

    float acc[16];
#pragma unroll
    for (int k = 0; k < 16; ++k) acc[k] = 0.f;

    for (int r = 0; r < 4; ++r) {
        int nb = r * 64;
        __syncthreads();
        {
            int n = t & 63; int c0 = t >> 6;
#pragma unroll
            for (int k = 0; k < 16; ++k) {
                int cc = c0 * 16 + k;
                f2s[cc][n] = f2[((size_t)(b * 64 + cc) << 8) + nb + n];
                g2t[n][cc] = g2[((size_t)(b * 64 + cc) << 8) + nb + n];
            }
        }
        __syncthreads();
        for (int n = 0; n < 64; ++n) {
            float fvv = f2s[c][n];
#pragma unroll
            for (int jj = 0; jj < 4; ++jj) {
                float4 gv = *reinterpret_cast<const float4*>(&g2t[n][d0 + jj * 4]);
                acc[jj * 4 + 0] = fmaf(fvv, gv.x, acc[jj * 4 + 0]);
                acc[jj * 4 + 1] = fmaf(fvv, gv.y, acc[jj * 4 + 1]);
                acc[jj * 4 + 2] = fmaf(fvv, gv.z, acc[jj * 4 + 2]);
                acc[jj * 4 + 3] = fmaf(fvv, gv.w, acc[jj * 4 + 3]);
            }
        }
    }
    __syncthreads();
#pragma unroll
    for (int k = 0; k < 16; ++k) s2s[c][d0 + k] = acc[k];
    __syncthreads();
    if (t < 64) {
        int d = t;
        float mx = s2s[0][d];
        for (int cc = 1; cc < 64; ++cc) mx = fmaxf(mx, s2s[cc][d]);
        float sm = 0.f;
        for (int cc = 0; cc < 64; ++cc) sm += __expf(s2s[cc][d] - mx);
        float r = 1.f / sm;
        for (int cc = 0; cc < 64; ++cc)
            beta2[((size_t)b << 12) + cc * 64 + d] = __expf(s2s[cc][d] - mx) * r;
    }
}

// ---------------------------------------------------------------------------
// out[b,d,n] = sum_c h2[b,c,n]*beta2[b,c,d] + x[b,d,n]. grid = B*64, block 256.
// ---------------------------------------------------------------------------
__global__ __launch_bounds__(256) void o2_residual_kernel(
    const ushort* __restrict__ h2b, const float* __restrict__ beta2,
    const float* __restrict__ x, float* __restrict__ out)
{
    __shared__ __align__(16) float b2s[64][64];   // [c][d]
    __shared__ float h2s[64][65];
    int t = threadIdx.x;
    int b = blockIdx.x >> 6;
    int n0 = (blockIdx.x & 63) << 6;

    {
#pragma unroll
        for (int k = 0; k < 16; ++k) {
            int idx = k * 256 + t;
            b2s[idx >> 6][idx & 63] = beta2[((size_t)b << 12) + idx];
        }
        int n = t & 63; int c0 = t >> 6;
#pragma unroll
        for (int k = 0; k < 16; ++k) {
            int cc = c0 * 16 + k;
            h2s[cc][n] = bf2f(h2b[((size_t)(b * 64 + cc) << 12) + n0 + n]);
        }
    }
    __syncthreads();

    int n = t & 63, dg = t >> 6, d0 = dg * 16;
    float acc[16];
#pragma unroll
    for (int k = 0; k < 16; ++k) acc[k] = 0.f;

    for (int cc = 0; cc < 64; ++cc) {
        float hv = h2s[cc][n];
#pragma unroll
        for (int jj = 0; jj < 4; ++jj) {
            float4 bv = *reinterpret_cast<const float4*>(&b2s[cc][d0 + jj * 4]);
            acc[jj * 4 + 0] = fmaf(hv, bv.x, acc[jj * 4 + 0]);
            acc[jj * 4 + 1] = fmaf(hv, bv.y, acc[jj * 4 + 1]);
            acc[jj * 4 + 2] = fmaf(hv, bv.z, acc[jj * 4 + 2]);
            acc[jj * 4 + 3] = fmaf(hv, bv.w, acc[jj * 4 + 3]);
        }
    }
#pragma unroll
    for (int k = 0; k < 16; ++k) {
        int d = d0 + k;
        size_t o = ((size_t)(b * 64 + d) << 12) + n0 + n;
        out[o] = acc[k] + x[o];
    }
}

// ---------------------------------------------------------------------------
extern "C" void kernel_launch(void* const* d_in, const int* in_sizes, int n_in,
                              void* d_out, int out_size, void* d_ws, size_t ws_size,
                              hipStream_t stream)
{
    const float* x  = (const float*)d_in[0];
    const float* w1 = (const float*)d_in[1];
    const float* b1 = (const float*)d_in[2];
    const float* w2 = (const float*)d_in[3];
    const float* b2 = (const float*)d_in[4];
    const float* w3 = (const float*)d_in[5];
    const float* b3 = (const float*)d_in[6];
    const float* w4 = (const float*)d_in[7];
    const float* b4 = (const float*)d_in[8];
    const float* w5 = (const float*)d_in[9];
    const float* b5 = (const float*)d_in[10];
    const float* w6 = (const float*)d_in[11];
    const float* b6 = (const float*)d_in[12];
    float* out = (float*)d_out;

    ushort* u = (ushort*)d_ws;
    ushort* fT  = u;                  // 131072 elems
    ushort* gT  = fT + 131072;        // 131072
    ushort* hhb = gT + 131072;        // 1048576
    ushort* x2p = hhb + 1048576;      // 1254400 (4*70*70*64), padded
    ushort* h2b = x2p + 1254400;      // 1048576
    ushort* Wt  = h2b + 1048576;      // 401408 (2*64*49*64)
    float* fr    = (float*)(Wt + 401408);
    float* f2    = fr;                // 65536
    float* g2    = fr + 65536;        // 65536
    float* beta2 = fr + 131072;       // 16384
    float* part  = fr + 147456;       // 917504 (7*8*64*256)

    produce_fgh<<<256, 256, 0, stream>>>(x, w1, b1, w2, b2, w3, b3, fT, gT, hhb);
    wt_kernel<<<128, 256, 0, stream>>>(w4, w5, Wt);
    hipMemsetAsync(x2p, 0, (size_t)4 * X2P_B * sizeof(ushort), stream);
    attn_kernel<<<256, 256, 0, stream>>>(fT, gT, hhb, w6, b6, x2p, h2b);
    conv7_split_kernel<<<224, 256, 0, stream>>>(x2p, Wt, part);
    conv7_reduce_kernel<<<128, 256, 0, stream>>>(part, b4, b5, f2, g2);
    s2_softmax_kernel<<<BB, 256, 0, stream>>>(f2, g2, beta2);
    o2_residual_kernel<<<256, 256, 0, stream>>>(h2b, beta2, x, out);
}

// Round 5
// 110.170 us; speedup vs baseline: 5.1015x; 1.2557x over previous
//
#include <hip/hip_runtime.h>
#include <math.h>

#define BB 4
#define CC 64
#define CRR 8
#define NN 4096

typedef __attribute__((ext_vector_type(8))) short bf16x8;
typedef __attribute__((ext_vector_type(4))) float f32x4;

__device__ inline float bf2f(ushort u) {
    union { uint i; float f; } v; v.i = (uint)u << 16; return v.f;
}
__device__ inline ushort f2bf(float f) {
    uint u = __builtin_bit_cast(uint, f);
    u = (u + 0x7FFFu + ((u >> 16) & 1u)) >> 16;
    return (ushort)u;
}
__device__ inline uint bfpack2(float a, float b) {
    uint ua = __builtin_bit_cast(uint, a);
    uint ub = __builtin_bit_cast(uint, b);
    ua = (ua + 0x7FFFu + ((ua >> 16) & 1u)) >> 16;
    ub = (ub + 0x7FFFu + ((ub >> 16) & 1u)) & 0xFFFF0000u;
    return ua | ub;
}

// x2p padded pixel-major: [b][py 70][px 70][ci 64] bf16, pad=3
#define X2P_B 313600   // 70*70*64

// ---------------------------------------------------------------------------
// Producer: f = conv1x1(x,w1,b1), g = conv1x1(x,w2,b2), hh = conv1x1(x,w3,b3)
// ---------------------------------------------------------------------------
__global__ __launch_bounds__(256) void produce_fgh(
    const float* __restrict__ x,
    const float* __restrict__ w1, const float* __restrict__ b1,
    const float* __restrict__ w2, const float* __restrict__ b2,
    const float* __restrict__ w3, const float* __restrict__ b3,
    ushort* __restrict__ fT, ushort* __restrict__ gT, ushort* __restrict__ hhb)
{
    int t = threadIdx.x;
    int b = blockIdx.x >> 6;
    int n = ((blockIdx.x & 63) << 6) + (t & 63);
    int og = __builtin_amdgcn_readfirstlane(t >> 6);  // wave-uniform

    const float* xb = x + ((size_t)b << 18) + n;
    float xv[64];
#pragma unroll
    for (int c = 0; c < 64; ++c) xv[c] = xb[(size_t)c << 12];

    if (og == 0) {
        ushort fo[8], go[8];
#pragma unroll
        for (int k = 0; k < 8; ++k) {
            float a1 = b1[k], a2 = b2[k];
#pragma unroll
            for (int c = 0; c < 64; ++c) {
                a1 = fmaf(w1[k * 64 + c], xv[c], a1);
                a2 = fmaf(w2[k * 64 + c], xv[c], a2);
            }
            fo[k] = f2bf(a1); go[k] = f2bf(a2);
        }
        uint4 fq = make_uint4((uint)fo[0] | ((uint)fo[1] << 16),
                              (uint)fo[2] | ((uint)fo[3] << 16),
                              (uint)fo[4] | ((uint)fo[5] << 16),
                              (uint)fo[6] | ((uint)fo[7] << 16));
        uint4 gq = make_uint4((uint)go[0] | ((uint)go[1] << 16),
                              (uint)go[2] | ((uint)go[3] << 16),
                              (uint)go[4] | ((uint)go[5] << 16),
                              (uint)go[6] | ((uint)go[7] << 16));
        *(uint4*)&fT[((size_t)b << 15) + (size_t)n * 8] = fq;
        *(uint4*)&gT[((size_t)b << 15) + (size_t)n * 8] = gq;
#pragma unroll
        for (int k = 0; k < 4; ++k) {
            float a = b3[k];
#pragma unroll
            for (int c = 0; c < 64; ++c) a = fmaf(w3[k * 64 + c], xv[c], a);
            hhb[((size_t)b << 18) + ((size_t)k << 12) + n] = f2bf(a);
        }
    } else {
        int c0 = og * 20 - 16;  // 4, 24, 44
#pragma unroll
        for (int k = 0; k < 20; ++k) {
            float a = b3[c0 + k];
#pragma unroll
            for (int c = 0; c < 64; ++c) a = fmaf(w3[(c0 + k) * 64 + c], xv[c], a);
            hhb[((size_t)b << 18) + ((size_t)(c0 + k) << 12) + n] = f2bf(a);
        }
    }
}

// ---------------------------------------------------------------------------
// Weight transform: Wt[conv][co][ky*7+kx][ci] (bf16) from OIHW fp32.
// ---------------------------------------------------------------------------
__global__ __launch_bounds__(256) void wt_kernel(
    const float* __restrict__ w4, const float* __restrict__ w5,
    ushort* __restrict__ Wt)
{
    int bid = blockIdx.x;
    int conv = bid >> 6, co = bid & 63;
    const float* W = conv ? w5 : w4;
    int t = threadIdx.x;
    for (int i = t; i < 3136; i += 256) {
        int ci = i / 49, kk = i - ci * 49;
        Wt[(((size_t)(conv * 64 + co)) * 49 + kk) * 64 + ci] = f2bf(W[co * 3136 + i]);
    }
}

// ---------------------------------------------------------------------------
// Fused MFMA flash attention + h2 epilogue. 1024 threads = 16 waves =
// 4 n-split quads x 4 m-strips. In-LDS combine of the 4 n-partials.
// grid = B*64 (64 m-cols per wg).
// ---------------------------------------------------------------------------
__global__ __launch_bounds__(1024) void attn_kernel(
    const ushort* __restrict__ fT, const ushort* __restrict__ gT,
    const ushort* __restrict__ hhb, const float* __restrict__ w6,
    const float* __restrict__ b6,
    ushort* __restrict__ x2p, ushort* __restrict__ h2b)
{
    __shared__ __align__(16) char smem[106496];
    // main-loop views
    ushort* hhT = (ushort*)smem;                 // [4 quad][2 buf][4096]
    ushort* fTl = (ushort*)(smem + 65536);       // [4 quad][2 buf][512]
    ushort* PstB = (ushort*)(smem + 73728);      // [16 wave][1024]
    // combine views (reused after barrier)
    float* Acc = (float*)smem;                   // [4 q][64 m][68]
    float* Mq  = (float*)(smem + 69632);         // [4][64]
    float* Lq  = (float*)(smem + 70656);         // [4][64]
    ushort* x2s = (ushort*)(smem + 71680);       // [64 m][72]

    int t = threadIdx.x;
    int q = t >> 8, tq = t & 255;
    int l = t & 63;
    int wq = tq >> 6;                 // m-strip within quad
    int w16 = t >> 6;                 // global wave id
    int ml = l & 15, g = l >> 4;
    int b = blockIdx.x >> 6;
    int m0 = (blockIdx.x & 63) << 6;
    int col = m0 + wq * 16 + ml;

    const ushort* fTb = fT + ((size_t)b << 15) + (size_t)q * 8192;
    const ushort* gTb = gT + ((size_t)b << 15);
    const ushort* hhB = hhb + ((size_t)b << 18) + (q << 10);

    const bf16x8 z8 = {0, 0, 0, 0, 0, 0, 0, 0};
    const f32x4 z4 = {0.f, 0.f, 0.f, 0.f};

    bf16x8 gfrag = *(const bf16x8*)(gTb + (size_t)col * 8);
    if (g != 0) gfrag = z8;

    int sc = tq >> 2, sp = tq & 3;
    const ushort* hrowBase = hhB + (size_t)sc * 4096 + sp * 16;
    int hdst = q * 8192 + sp * 1024 + sc * 8;    // hhT[q][0] base; +4096 per buf

    uint4 h0 = *(const uint4*)(hrowBase);
    uint4 h1 = *(const uint4*)(hrowBase + 8);
    uint4 fv = make_uint4(0, 0, 0, 0);
    if (tq < 64) fv = *(const uint4*)(fTb + (size_t)tq * 8);
    *(uint4*)&hhT[hdst] = h0;
    *(uint4*)&hhT[hdst + 512] = h1;
    if (tq < 64) *(uint4*)&fTl[q * 1024 + tq * 8] = fv;

    f32x4 acc[4] = {z4, z4, z4, z4};
    float M = -3e38f, L = 0.f;
    int swz = (ml & 7) << 4;
    char* pbase = (char*)PstB + w16 * 2048;
    __syncthreads();

    for (int nt = 0; nt < 16; ++nt) {
        int buf = nt & 1;
        if (nt < 15) {
            int n0 = (nt + 1) << 6;
            h0 = *(const uint4*)(hrowBase + n0);
            h1 = *(const uint4*)(hrowBase + n0 + 8);
            if (tq < 64) fv = *(const uint4*)(fTb + (size_t)(n0 + tq) * 8);
        }

        f32x4 Sv[4];
#pragma unroll
        for (int s = 0; s < 4; ++s) {
            bf16x8 af = *(const bf16x8*)&fTl[q * 1024 + buf * 512 + (16 * s + ml) * 8];
            Sv[s] = __builtin_amdgcn_mfma_f32_16x16x32_bf16(af, gfrag, z4, 0, 0, 0);
        }

        float tmax = Sv[0][0];
#pragma unroll
        for (int s = 0; s < 4; ++s)
#pragma unroll
            for (int r = 0; r < 4; ++r) tmax = fmaxf(tmax, Sv[s][r]);
        tmax = fmaxf(tmax, __shfl_xor(tmax, 16));
        tmax = fmaxf(tmax, __shfl_xor(tmax, 32));
        float Mn = fmaxf(M, tmax);
        if (!__all(tmax <= M)) {           // rescale only when max grew (bit-exact)
            float scl = __expf(M - Mn);
#pragma unroll
            for (int ct = 0; ct < 4; ++ct) acc[ct] *= scl;
            L *= scl;
            M = Mn;
        }
        float rsum = 0.f;
        uint plo[4], phi[4];
#pragma unroll
        for (int s = 0; s < 4; ++s) {
            float p0 = __expf(Sv[s][0] - M);
            float p1 = __expf(Sv[s][1] - M);
            float p2 = __expf(Sv[s][2] - M);
            float p3 = __expf(Sv[s][3] - M);
            rsum += (p0 + p1) + (p2 + p3);
            plo[s] = bfpack2(p0, p1);
            phi[s] = bfpack2(p2, p3);
        }
        rsum += __shfl_xor(rsum, 16);
        rsum += __shfl_xor(rsum, 32);
        L += rsum;

#pragma unroll
        for (int s = 0; s < 4; ++s) {
            uint off = (uint)((ml * 128 + 32 * s + 8 * g) ^ swz);
            *(uint2*)(pbase + off) = make_uint2(plo[s], phi[s]);
        }

#pragma unroll
        for (int kk = 0; kk < 2; ++kk) {
            uint off = (uint)((ml * 128 + 64 * kk + 16 * g) ^ swz);
            bf16x8 pf = *(const bf16x8*)(pbase + off);
#pragma unroll
            for (int ct = 0; ct < 4; ++ct) {
                bf16x8 hf = *(const bf16x8*)&hhT[q * 8192 + buf * 4096 + (kk * 4 + g) * 512 + (16 * ct + ml) * 8];
                acc[ct] = __builtin_amdgcn_mfma_f32_16x16x32_bf16(hf, pf, acc[ct], 0, 0, 0);
            }
        }

        if (nt < 15) {
            int nb = (nt + 1) & 1;
            *(uint4*)&hhT[hdst + nb * 4096] = h0;
            *(uint4*)&hhT[hdst + nb * 4096 + 512] = h1;
            if (tq < 64) *(uint4*)&fTl[q * 1024 + nb * 512 + tq * 8] = fv;
        }
        __syncthreads();
    }

    // ---- write quad partials to LDS ----
    {
        float* arow = Acc + q * 4352 + (wq * 16 + ml) * 68;
#pragma unroll
        for (int ct = 0; ct < 4; ++ct)
            *(f32x4*)(arow + 16 * ct + 4 * g) = acc[ct];
        if (g == 0) {
            Mq[q * 64 + wq * 16 + ml] = M;
            Lq[q * 64 + wq * 16 + ml] = L;
        }
    }
    __syncthreads();

    // ---- combine: thread (m = t>>4, c0 = (t&15)*4) ----
    {
        int m = t >> 4, c0 = (t & 15) << 2;
        float Ms = Mq[m];
        Ms = fmaxf(Ms, Mq[64 + m]);
        Ms = fmaxf(Ms, Mq[128 + m]);
        Ms = fmaxf(Ms, Mq[192 + m]);
        float al0 = __expf(Mq[m] - Ms);
        float al1 = __expf(Mq[64 + m] - Ms);
        float al2 = __expf(Mq[128 + m] - Ms);
        float al3 = __expf(Mq[192 + m] - Ms);
        float Ltot = al0 * Lq[m] + al1 * Lq[64 + m] + al2 * Lq[128 + m] + al3 * Lq[192 + m];
        float rL = 1.f / Ltot;
        f32x4 v0 = *(const f32x4*)(Acc + 0 * 4352 + m * 68 + c0);
        f32x4 v1 = *(const f32x4*)(Acc + 1 * 4352 + m * 68 + c0);
        f32x4 v2 = *(const f32x4*)(Acc + 2 * 4352 + m * 68 + c0);
        f32x4 v3 = *(const f32x4*)(Acc + 3 * 4352 + m * 68 + c0);
        f32x4 v;
#pragma unroll
        for (int r = 0; r < 4; ++r)
            v[r] = (al0 * v0[r] + al1 * v1[r] + al2 * v2[r] + al3 * v3[r]) * rL;
        uint2 pk = make_uint2(bfpack2(v[0], v[1]), bfpack2(v[2], v[3]));
        int px = m + 3, py = (blockIdx.x & 63) + 3;
        *(uint2*)(x2p + (size_t)b * X2P_B + (size_t)(py * 70 + px) * 64 + c0) = pk;
        *(uint2*)(x2s + m * 72 + c0) = pk;
    }
    __syncthreads();

    // ---- h2 epilogue: wave w16 -> (d-strip, m-strip) tile, 2 MFMAs ----
    {
        int dt = w16 & 3, mq = w16 >> 2;
        f32x4 hacc = z4;
#pragma unroll
        for (int kk = 0; kk < 2; ++kk) {
            bf16x8 xf = *(const bf16x8*)(x2s + (mq * 16 + ml) * 72 + 32 * kk + 8 * g);
            const float* wr = w6 + (16 * dt + ml) * 64 + 32 * kk + 8 * g;
            float4 wa = *(const float4*)wr;
            float4 wb = *(const float4*)(wr + 4);
            bf16x8 wf;
            wf[0] = (short)f2bf(wa.x); wf[1] = (short)f2bf(wa.y);
            wf[2] = (short)f2bf(wa.z); wf[3] = (short)f2bf(wa.w);
            wf[4] = (short)f2bf(wb.x); wf[5] = (short)f2bf(wb.y);
            wf[6] = (short)f2bf(wb.z); wf[7] = (short)f2bf(wb.w);
            hacc = __builtin_amdgcn_mfma_f32_16x16x32_bf16(wf, xf, hacc, 0, 0, 0);
        }
        ushort* h2row = h2b + ((size_t)b << 18) + (m0 + mq * 16 + ml);
#pragma unroll
        for (int r = 0; r < 4; ++r) {
            int d = 16 * dt + 4 * g + r;
            h2row[(size_t)d << 12] = f2bf(hacc[r] + b6[d]);
        }
    }
}

// ---------------------------------------------------------------------------
// 7x7 stride-4 conv, ky-split implicit GEMM. grid = 224 wgs (896 waves).
// part[ky][b*2+conv][co][opix] fp32 partial sums.
// ---------------------------------------------------------------------------
__global__ __launch_bounds__(256) void conv7_split_kernel(
    const ushort* __restrict__ x2p, const ushort* __restrict__ Wt,
    float* __restrict__ part)
{
    int t = threadIdx.x;
    int l = t & 63, w = t >> 6;
    int ml = l & 15, g = l >> 4;
    int W = blockIdx.x * 4 + w;           // 0..895
    int og = W & 3;                       // opix quarter (4 tiles of 16)
    int ct = (W >> 2) & 3;                // co tile
    int rest = W >> 4;                    // 0..55
    int ky = rest % 7;
    int bc = rest / 7;                    // b*2+conv
    int conv = bc & 1, b = bc >> 1;

    int co0 = ct * 16;
    const ushort* wb = Wt + (size_t)conv * 200704
                     + (size_t)(co0 + ml) * 3136 + (size_t)(ky * 7) * 64 + g * 8;
    const ushort* xbase = x2p + (size_t)b * X2P_B + g * 8;

    int pixoff[4];
#pragma unroll
    for (int s = 0; s < 4; ++s) {
        int opix = og * 64 + s * 16 + ml;
        int oy = opix >> 4, ox = opix & 15;
        pixoff[s] = ((oy * 4 + ky) * 70 + ox * 4) * 64;
    }

    const f32x4 z4 = {0.f, 0.f, 0.f, 0.f};
    f32x4 acc[4] = {z4, z4, z4, z4};

#pragma unroll
    for (int kx = 0; kx < 7; ++kx) {
#pragma unroll
        for (int ci0 = 0; ci0 < 64; ci0 += 32) {
            bf16x8 av = *(const bf16x8*)(wb + kx * 64 + ci0);
#pragma unroll
            for (int s = 0; s < 4; ++s) {
                bf16x8 bv = *(const bf16x8*)(xbase + pixoff[s] + kx * 64 + ci0);
                acc[s] = __builtin_amdgcn_mfma_f32_16x16x32_bf16(av, bv, acc[s], 0, 0, 0);
            }
        }
    }

    float* pb = part + (size_t)(ky * 8 + bc) * 16384;
#pragma unroll
    for (int s = 0; s < 4; ++s) {
        int opix = og * 64 + s * 16 + ml;
#pragma unroll
        for (int r = 0; r < 4; ++r) {
            int co = co0 + 4 * g + r;
            pb[co * 256 + opix] = acc[s][r];
        }
    }
}

// ---------------------------------------------------------------------------
// Reduce 7 ky-partials + bias -> f2/g2. grid = 128, block = 256, float4/thr.
// ---------------------------------------------------------------------------
__global__ __launch_bounds__(256) void conv7_reduce_kernel(
    const float* __restrict__ part, const float* __restrict__ b4,
    const float* __restrict__ b5, float* __restrict__ f2, float* __restrict__ g2)
{
    int idx = (blockIdx.x * 256 + threadIdx.x) * 4;   // over 131072 floats
    int bc = idx >> 14;
    int co = (idx >> 8) & 63;
    int conv = bc & 1, b = bc >> 1;
    int sub = idx & 16383;
    float4 s = make_float4(0.f, 0.f, 0.f, 0.f);
#pragma unroll
    for (int ky = 0; ky < 7; ++ky) {
        float4 v = *(const float4*)&part[(size_t)(ky * 8 + bc) * 16384 + sub];
        s.x += v.x; s.y += v.y; s.z += v.z; s.w += v.w;
    }
    float bias = (conv ? b5 : b4)[co];
    s.x += bias; s.y += bias; s.z += bias; s.w += bias;
    float* y = conv ? g2 : f2;
    *(float4*)&y[(size_t)b * 16384 + sub] = s;
}

// ---------------------------------------------------------------------------
// s2[c,d] = sum_n f2[c,n]*g2[d,n]; beta2 = softmax_c(s2). grid = B, block 256.
// ---------------------------------------------------------------------------
__global__ __launch_bounds__(256) void s2_softmax_kernel(
    const float* __restrict__ f2, const float* __restrict__ g2,
    float* __restrict__ beta2)
{
    __shared__ float f2s[64][65];
    __shared__ __align__(16) float g2t[64][68];   // [n][d]
    __shared__ float s2s[64][65];
    int t = threadIdx.x;
    int b = blockIdx.x;
    int c = t & 63, dg = t >> 6, d0 = dg * 16;

    float acc[16];
#pragma unroll
    for (int k = 0; k < 16; ++k) acc[k] = 0.f;

    for (int r = 0; r < 4; ++r) {
        int nb = r * 64;
        __syncthreads();
        {
            int n = t & 63; int c0 = t >> 6;
#pragma unroll
            for (int k = 0; k < 16; ++k) {
                int cc = c0 * 16 + k;
                f2s[cc][n] = f2[((size_t)(b * 64 + cc) << 8) + nb + n];
                g2t[n][cc] = g2[((size_t)(b * 64 + cc) << 8) + nb + n];
            }
        }
        __syncthreads();
        for (int n = 0; n < 64; ++n) {
            float fvv = f2s[c][n];
#pragma unroll
            for (int jj = 0; jj < 4; ++jj) {
                float4 gv = *reinterpret_cast<const float4*>(&g2t[n][d0 + jj * 4]);
                acc[jj * 4 + 0] = fmaf(fvv, gv.x, acc[jj * 4 + 0]);
                acc[jj * 4 + 1] = fmaf(fvv, gv.y, acc[jj * 4 + 1]);
                acc[jj * 4 + 2] = fmaf(fvv, gv.z, acc[jj * 4 + 2]);
                acc[jj * 4 + 3] = fmaf(fvv, gv.w, acc[jj * 4 + 3]);
            }
        }
    }
    __syncthreads();
#pragma unroll
    for (int k = 0; k < 16; ++k) s2s[c][d0 + k] = acc[k];
    __syncthreads();
    if (t < 64) {
        int d = t;
        float mx = s2s[0][d];
        for (int cc = 1; cc < 64; ++cc) mx = fmaxf(mx, s2s[cc][d]);
        float sm = 0.f;
        for (int cc = 0; cc < 64; ++cc) sm += __expf(s2s[cc][d] - mx);
        float r = 1.f / sm;
        for (int cc = 0; cc < 64; ++cc)
            beta2[((size_t)b << 12) + cc * 64 + d] = __expf(s2s[cc][d] - mx) * r;
    }
}

// ---------------------------------------------------------------------------
// out[b,d,n] = sum_c h2[b,c,n]*beta2[b,c,d] + x[b,d,n]. grid = B*64, block 256.
// ---------------------------------------------------------------------------
__global__ __launch_bounds__(256) void o2_residual_kernel(
    const ushort* __restrict__ h2b, const float* __restrict__ beta2,
    const float* __restrict__ x, float* __restrict__ out)
{
    __shared__ __align__(16) float b2s[64][64];   // [c][d]
    __shared__ float h2s[64][65];
    int t = threadIdx.x;
    int b = blockIdx.x >> 6;
    int n0 = (blockIdx.x & 63) << 6;

    {
#pragma unroll
        for (int k = 0; k < 16; ++k) {
            int idx = k * 256 + t;
            b2s[idx >> 6][idx & 63] = beta2[((size_t)b << 12) + idx];
        }
        int n = t & 63; int c0 = t >> 6;
#pragma unroll
        for (int k = 0; k < 16; ++k) {
            int cc = c0 * 16 + k;
            h2s[cc][n] = bf2f(h2b[((size_t)(b * 64 + cc) << 12) + n0 + n]);
        }
    }
    __syncthreads();

    int n = t & 63, dg = t >> 6, d0 = dg * 16;
    float acc[16];
#pragma unroll
    for (int k = 0; k < 16; ++k) acc[k] = 0.f;

    for (int cc = 0; cc < 64; ++cc) {
        float hv = h2s[cc][n];
#pragma unroll
        for (int jj = 0; jj < 4; ++jj) {
            float4 bv = *reinterpret_cast<const float4*>(&b2s[cc][d0 + jj * 4]);
            acc[jj * 4 + 0] = fmaf(hv, bv.x, acc[jj * 4 + 0]);
            acc[jj * 4 + 1] = fmaf(hv, bv.y, acc[jj * 4 + 1]);
            acc[jj * 4 + 2] = fmaf(hv, bv.z, acc[jj * 4 + 2]);
            acc[jj * 4 + 3] = fmaf(hv, bv.w, acc[jj * 4 + 3]);
        }
    }
#pragma unroll
    for (int k = 0; k < 16; ++k) {
        int d = d0 + k;
        size_t o = ((size_t)(b * 64 + d) << 12) + n0 + n;
        out[o] = acc[k] + x[o];
    }
}

// ---------------------------------------------------------------------------
extern "C" void kernel_launch(void* const* d_in, const int* in_sizes, int n_in,
                              void* d_out, int out_size, void* d_ws, size_t ws_size,
                              hipStream_t stream)
{
    const float* x  = (const float*)d_in[0];
    const float* w1 = (const float*)d_in[1];
    const float* b1 = (const float*)d_in[2];
    const float* w2 = (const float*)d_in[3];
    const float* b2 = (const float*)d_in[4];
    const float* w3 = (const float*)d_in[5];
    const float* b3 = (const float*)d_in[6];
    const float* w4 = (const float*)d_in[7];
    const float* b4 = (const float*)d_in[8];
    const float* w5 = (const float*)d_in[9];
    const float* b5 = (const float*)d_in[10];
    const float* w6 = (const float*)d_in[11];
    const float* b6 = (const float*)d_in[12];
    float* out = (float*)d_out;

    ushort* u = (ushort*)d_ws;
    ushort* fT  = u;                  // 131072 elems
    ushort* gT  = fT + 131072;        // 131072
    ushort* hhb = gT + 131072;        // 1048576
    ushort* x2p = hhb + 1048576;      // 1254400 (4*70*70*64), padded
    ushort* h2b = x2p + 1254400;      // 1048576
    ushort* Wt  = h2b + 1048576;      // 401408 (2*64*49*64)
    float* fr    = (float*)(Wt + 401408);
    float* f2    = fr;                // 65536
    float* g2    = fr + 65536;        // 65536
    float* beta2 = fr + 131072;       // 16384
    float* part  = fr + 147456;       // 917504 (7*8*64*256)

    produce_fgh<<<256, 256, 0, stream>>>(x, w1, b1, w2, b2, w3, b3, fT, gT, hhb);
    wt_kernel<<<128, 256, 0, stream>>>(w4, w5, Wt);
    hipMemsetAsync(x2p, 0, (size_t)4 * X2P_B * sizeof(ushort), stream);
    attn_kernel<<<256, 1024, 0, stream>>>(fT, gT, hhb, w6, b6, x2p, h2b);
    conv7_split_kernel<<<224, 256, 0, stream>>>(x2p, Wt, part);
    conv7_reduce_kernel<<<128, 256, 0, stream>>>(part, b4, b5, f2, g2);
    s2_softmax_kernel<<<BB, 256, 0, stream>>>(f2, g2, beta2);
    o2_residual_kernel<<<256, 256, 0, stream>>>(h2b, beta2, x, out);
}

// Round 6
// 105.146 us; speedup vs baseline: 5.3452x; 1.0478x over previous
//
#include <hip/hip_runtime.h>
#include <math.h>

#define BB 4
#define CC 64
#define CRR 8
#define NN 4096

typedef __attribute__((ext_vector_type(8))) short bf16x8;
typedef __attribute__((ext_vector_type(4))) float f32x4;

__device__ inline float bf2f(ushort u) {
    union { uint i; float f; } v; v.i = (uint)u << 16; return v.f;
}
__device__ inline ushort f2bf(float f) {
    uint u = __builtin_bit_cast(uint, f);
    u = (u + 0x7FFFu + ((u >> 16) & 1u)) >> 16;
    return (ushort)u;
}
__device__ inline uint bfpack2(float a, float b) {
    uint ua = __builtin_bit_cast(uint, a);
    uint ub = __builtin_bit_cast(uint, b);
    ua = (ua + 0x7FFFu + ((ua >> 16) & 1u)) >> 16;
    ub = (ub + 0x7FFFu + ((ub >> 16) & 1u)) & 0xFFFF0000u;
    return ua | ub;
}
__device__ inline float fexp2(float x) {
#if __has_builtin(__builtin_amdgcn_exp2f)
    return __builtin_amdgcn_exp2f(x);
#else
    return exp2f(x);
#endif
}

// x2p padded pixel-major: [b][py 70][px 70][ci 64] bf16, pad=3
#define X2P_B 313600   // 70*70*64

// ---------------------------------------------------------------------------
// Producer: f = conv1x1(x,w1,b1) * log2(e)  (pre-scaled for exp2 softmax),
//           g = conv1x1(x,w2,b2), hh = conv1x1(x,w3,b3)
// ---------------------------------------------------------------------------
__global__ __launch_bounds__(256) void produce_fgh(
    const float* __restrict__ x,
    const float* __restrict__ w1, const float* __restrict__ b1,
    const float* __restrict__ w2, const float* __restrict__ b2,
    const float* __restrict__ w3, const float* __restrict__ b3,
    ushort* __restrict__ fT, ushort* __restrict__ gT, ushort* __restrict__ hhb)
{
    const float LOG2E = 1.4426950408889634f;
    int t = threadIdx.x;
    int b = blockIdx.x >> 6;
    int n = ((blockIdx.x & 63) << 6) + (t & 63);
    int og = __builtin_amdgcn_readfirstlane(t >> 6);  // wave-uniform

    const float* xb = x + ((size_t)b << 18) + n;
    float xv[64];
#pragma unroll
    for (int c = 0; c < 64; ++c) xv[c] = xb[(size_t)c << 12];

    if (og == 0) {
        ushort fo[8], go[8];
#pragma unroll
        for (int k = 0; k < 8; ++k) {
            float a1 = b1[k], a2 = b2[k];
#pragma unroll
            for (int c = 0; c < 64; ++c) {
                a1 = fmaf(w1[k * 64 + c], xv[c], a1);
                a2 = fmaf(w2[k * 64 + c], xv[c], a2);
            }
            fo[k] = f2bf(a1 * LOG2E); go[k] = f2bf(a2);
        }
        uint4 fq = make_uint4((uint)fo[0] | ((uint)fo[1] << 16),
                              (uint)fo[2] | ((uint)fo[3] << 16),
                              (uint)fo[4] | ((uint)fo[5] << 16),
                              (uint)fo[6] | ((uint)fo[7] << 16));
        uint4 gq = make_uint4((uint)go[0] | ((uint)go[1] << 16),
                              (uint)go[2] | ((uint)go[3] << 16),
                              (uint)go[4] | ((uint)go[5] << 16),
                              (uint)go[6] | ((uint)go[7] << 16));
        *(uint4*)&fT[((size_t)b << 15) + (size_t)n * 8] = fq;
        *(uint4*)&gT[((size_t)b << 15) + (size_t)n * 8] = gq;
#pragma unroll
        for (int k = 0; k < 4; ++k) {
            float a = b3[k];
#pragma unroll
            for (int c = 0; c < 64; ++c) a = fmaf(w3[k * 64 + c], xv[c], a);
            hhb[((size_t)b << 18) + ((size_t)k << 12) + n] = f2bf(a);
        }
    } else {
        int c0 = og * 20 - 16;  // 4, 24, 44
#pragma unroll
        for (int k = 0; k < 20; ++k) {
            float a = b3[c0 + k];
#pragma unroll
            for (int c = 0; c < 64; ++c) a = fmaf(w3[(c0 + k) * 64 + c], xv[c], a);
            hhb[((size_t)b << 18) + ((size_t)(c0 + k) << 12) + n] = f2bf(a);
        }
    }
}

// ---------------------------------------------------------------------------
// Weight transform: Wt[conv][co][ky*7+kx][ci] (bf16) from OIHW fp32.
// ---------------------------------------------------------------------------
__global__ __launch_bounds__(256) void wt_kernel(
    const float* __restrict__ w4, const float* __restrict__ w5,
    ushort* __restrict__ Wt)
{
    int bid = blockIdx.x;
    int conv = bid >> 6, co = bid & 63;
    const float* W = conv ? w5 : w4;
    int t = threadIdx.x;
    for (int i = t; i < 3136; i += 256) {
        int ci = i / 49, kk = i - ci * 49;
        Wt[(((size_t)(conv * 64 + co)) * 49 + kk) * 64 + ci] = f2bf(W[co * 3136 + i]);
    }
}

// ---------------------------------------------------------------------------
// Zero only the 3-pixel halo of x2p (interior is fully rewritten by attn).
// 804 halo pixels x 4 batches; one pixel (64ch = 128B) per thread.
// ---------------------------------------------------------------------------
__global__ __launch_bounds__(256) void zero_halo_kernel(ushort* __restrict__ x2p)
{
    int gid = blockIdx.x * 256 + threadIdx.x;
    if (gid >= 4 * 804) return;
    int b = gid / 804;
    int i = gid - b * 804;
    int py, px;
    if (i < 210) { py = i / 70; px = i - py * 70; }
    else if (i < 420) { int j = i - 210; int r = j / 70; py = 67 + r; px = j - r * 70; }
    else { int j = i - 420; int r = j / 6; py = 3 + r; int c = j - r * 6; px = c < 3 ? c : 64 + c - 3; }
    ushort* p = x2p + (size_t)b * X2P_B + (size_t)(py * 70 + px) * 64;
    uint4 z = make_uint4(0, 0, 0, 0);
#pragma unroll
    for (int k = 0; k < 8; ++k) *(uint4*)(p + k * 8) = z;
}

// ---------------------------------------------------------------------------
// Fused MFMA flash attention + h2 epilogue. 1024 threads = 16 waves =
// 4 n-split quads x 4 m-strips. Fixed-base exp2 softmax (no max tracking,
// statistically safe: |s| <~ 24 << 127). In-LDS sum-combine of 4 n-partials.
// grid = B*64 (64 m-cols per wg).
// ---------------------------------------------------------------------------
__global__ __launch_bounds__(1024) void attn_kernel(
    const ushort* __restrict__ fT, const ushort* __restrict__ gT,
    const ushort* __restrict__ hhb, const float* __restrict__ w6,
    const float* __restrict__ b6,
    ushort* __restrict__ x2p, ushort* __restrict__ h2b)
{
    __shared__ __align__(16) char smem[98304];
    // main-loop views
    ushort* hhT = (ushort*)smem;                 // [4 quad][2 buf][4096]  64 KB
    ushort* PstB = (ushort*)(smem + 65536);      // [16 wave][1024]        32 KB
    // combine views (reused after final barrier)
    float* Acc = (float*)smem;                   // [4 q][64 m][68]
    float* Lq  = (float*)(smem + 69632);         // [4][64]
    ushort* x2s = (ushort*)(smem + 70656);       // [64 m][72]

    int t = threadIdx.x;
    int q = t >> 8, tq = t & 255;
    int l = t & 63;
    int wq = tq >> 6;                 // m-strip within quad
    int w16 = t >> 6;                 // global wave id
    int ml = l & 15, g = l >> 4;
    int b = blockIdx.x >> 6;
    int m0 = (blockIdx.x & 63) << 6;
    int col = m0 + wq * 16 + ml;

    const ushort* fTb = fT + ((size_t)b << 15) + (size_t)q * 8192;
    const ushort* gTb = gT + ((size_t)b << 15);
    const ushort* hhB = hhb + ((size_t)b << 18) + (q << 10);

    const bf16x8 z8 = {0, 0, 0, 0, 0, 0, 0, 0};
    const f32x4 z4 = {0.f, 0.f, 0.f, 0.f};

    bf16x8 gfrag = *(const bf16x8*)(gTb + (size_t)col * 8);
    if (g != 0) gfrag = z8;

    int sc = tq >> 2, sp = tq & 3;
    const ushort* hrowBase = hhB + (size_t)sc * 4096 + sp * 16;
    int hdst = q * 8192 + sp * 1024 + sc * 8;    // hhT[q][buf0]; +4096/buf

    // prologue: stage hh tile 0, load af (scores A-frags) for iter 0
    uint4 h0 = *(const uint4*)(hrowBase);
    uint4 h1 = *(const uint4*)(hrowBase + 8);
    *(uint4*)&hhT[hdst] = h0;
    *(uint4*)&hhT[hdst + 512] = h1;
    bf16x8 afc[4];
#pragma unroll
    for (int s = 0; s < 4; ++s)
        afc[s] = *(const bf16x8*)(fTb + (size_t)(16 * s + ml) * 8);

    f32x4 acc[4] = {z4, z4, z4, z4};
    float rsum = 0.f;
    int swz = (ml & 7) << 4;
    char* pbase = (char*)PstB + w16 * 2048;
    __syncthreads();

    for (int nt = 0; nt < 16; ++nt) {
        int buf = nt & 1;
        bf16x8 afn[4];
        if (nt < 15) {
            int n0 = (nt + 1) << 6;
            h0 = *(const uint4*)(hrowBase + n0);
            h1 = *(const uint4*)(hrowBase + n0 + 8);
#pragma unroll
            for (int s = 0; s < 4; ++s)
                afn[s] = *(const bf16x8*)(fTb + (size_t)(n0 + 16 * s + ml) * 8);
        }

        // ---- scores (f pre-scaled by log2e) ----
        f32x4 Sv[4];
        __builtin_amdgcn_s_setprio(1);
#pragma unroll
        for (int s = 0; s < 4; ++s)
            Sv[s] = __builtin_amdgcn_mfma_f32_16x16x32_bf16(afc[s], gfrag, z4, 0, 0, 0);
        __builtin_amdgcn_s_setprio(0);

        // ---- P = 2^s, accumulate denominator ----
        uint plo[4], phi[4];
#pragma unroll
        for (int s = 0; s < 4; ++s) {
            float p0 = fexp2(Sv[s][0]);
            float p1 = fexp2(Sv[s][1]);
            float p2 = fexp2(Sv[s][2]);
            float p3 = fexp2(Sv[s][3]);
            rsum += (p0 + p1) + (p2 + p3);
            plo[s] = bfpack2(p0, p1);
            phi[s] = bfpack2(p2, p3);
        }

        // ---- stage P (bf16) into per-wave swizzled LDS ----
#pragma unroll
        for (int s = 0; s < 4; ++s) {
            uint off = (uint)((ml * 128 + 32 * s + 8 * g) ^ swz);
            *(uint2*)(pbase + off) = make_uint2(plo[s], phi[s]);
        }

        // ---- PV ----
        __builtin_amdgcn_s_setprio(1);
#pragma unroll
        for (int kk = 0; kk < 2; ++kk) {
            uint off = (uint)((ml * 128 + 64 * kk + 16 * g) ^ swz);
            bf16x8 pf = *(const bf16x8*)(pbase + off);
#pragma unroll
            for (int ct = 0; ct < 4; ++ct) {
                bf16x8 hf = *(const bf16x8*)&hhT[q * 8192 + buf * 4096 + (kk * 4 + g) * 512 + (16 * ct + ml) * 8];
                acc[ct] = __builtin_amdgcn_mfma_f32_16x16x32_bf16(hf, pf, acc[ct], 0, 0, 0);
            }
        }
        __builtin_amdgcn_s_setprio(0);

        if (nt < 15) {
            int nb = (nt + 1) & 1;
            *(uint4*)&hhT[hdst + nb * 4096] = h0;
            *(uint4*)&hhT[hdst + nb * 4096 + 512] = h1;
#pragma unroll
            for (int s = 0; s < 4; ++s) afc[s] = afn[s];
        }
        __syncthreads();
    }

    // ---- denominator: reduce over the 4 g-lanes ----
    rsum += __shfl_xor(rsum, 16);
    rsum += __shfl_xor(rsum, 32);

    // ---- write quad partials to LDS ----
    {
        float* arow = Acc + q * 4352 + (wq * 16 + ml) * 68;
#pragma unroll
        for (int ct = 0; ct < 4; ++ct)
            *(f32x4*)(arow + 16 * ct + 4 * g) = acc[ct];
        if (g == 0) Lq[q * 64 + wq * 16 + ml] = rsum;
    }
    __syncthreads();

    // ---- combine (plain sums: all quads share base 2^0) ----
    {
        int m = t >> 4, c0 = (t & 15) << 2;
        float Ltot = Lq[m] + Lq[64 + m] + Lq[128 + m] + Lq[192 + m];
        float rL = 1.f / Ltot;
        f32x4 v0 = *(const f32x4*)(Acc + 0 * 4352 + m * 68 + c0);
        f32x4 v1 = *(const f32x4*)(Acc + 1 * 4352 + m * 68 + c0);
        f32x4 v2 = *(const f32x4*)(Acc + 2 * 4352 + m * 68 + c0);
        f32x4 v3 = *(const f32x4*)(Acc + 3 * 4352 + m * 68 + c0);
        f32x4 v;
#pragma unroll
        for (int r = 0; r < 4; ++r)
            v[r] = ((v0[r] + v1[r]) + (v2[r] + v3[r])) * rL;
        uint2 pk = make_uint2(bfpack2(v[0], v[1]), bfpack2(v[2], v[3]));
        int px = m + 3, py = (blockIdx.x & 63) + 3;
        *(uint2*)(x2p + (size_t)b * X2P_B + (size_t)(py * 70 + px) * 64 + c0) = pk;
        *(uint2*)(x2s + m * 72 + c0) = pk;
    }
    __syncthreads();

    // ---- h2 epilogue: wave w16 -> (d-strip, m-strip) tile, 2 MFMAs ----
    {
        int dt = w16 & 3, mq = w16 >> 2;
        f32x4 hacc = z4;
#pragma unroll
        for (int kk = 0; kk < 2; ++kk) {
            bf16x8 xf = *(const bf16x8*)(x2s + (mq * 16 + ml) * 72 + 32 * kk + 8 * g);
            const float* wr = w6 + (16 * dt + ml) * 64 + 32 * kk + 8 * g;
            float4 wa = *(const float4*)wr;
            float4 wb = *(const float4*)(wr + 4);
            bf16x8 wf;
            wf[0] = (short)f2bf(wa.x); wf[1] = (short)f2bf(wa.y);
            wf[2] = (short)f2bf(wa.z); wf[3] = (short)f2bf(wa.w);
            wf[4] = (short)f2bf(wb.x); wf[5] = (short)f2bf(wb.y);
            wf[6] = (short)f2bf(wb.z); wf[7] = (short)f2bf(wb.w);
            hacc = __builtin_amdgcn_mfma_f32_16x16x32_bf16(wf, xf, hacc, 0, 0, 0);
        }
        ushort* h2row = h2b + ((size_t)b << 18) + (m0 + mq * 16 + ml);
#pragma unroll
        for (int r = 0; r < 4; ++r) {
            int d = 16 * dt + 4 * g + r;
            h2row[(size_t)d << 12] = f2bf(hacc[r] + b6[d]);
        }
    }
}

// ---------------------------------------------------------------------------
// 7x7 stride-4 conv, ky-split implicit GEMM. grid = 224 wgs (896 waves).
// part[ky][b*2+conv][co][opix] fp32 partial sums.
// ---------------------------------------------------------------------------
__global__ __launch_bounds__(256) void conv7_split_kernel(
    const ushort* __restrict__ x2p, const ushort* __restrict__ Wt,
    float* __restrict__ part)
{
    int t = threadIdx.x;
    int l = t & 63, w = t >> 6;
    int ml = l & 15, g = l >> 4;
    int W = blockIdx.x * 4 + w;           // 0..895
    int og = W & 3;                       // opix quarter (4 tiles of 16)
    int ct = (W >> 2) & 3;                // co tile
    int rest = W >> 4;                    // 0..55
    int ky = rest % 7;
    int bc = rest / 7;                    // b*2+conv
    int conv = bc & 1, b = bc >> 1;

    int co0 = ct * 16;
    const ushort* wb = Wt + (size_t)conv * 200704
                     + (size_t)(co0 + ml) * 3136 + (size_t)(ky * 7) * 64 + g * 8;
    const ushort* xbase = x2p + (size_t)b * X2P_B + g * 8;

    int pixoff[4];
#pragma unroll
    for (int s = 0; s < 4; ++s) {
        int opix = og * 64 + s * 16 + ml;
        int oy = opix >> 4, ox = opix & 15;
        pixoff[s] = ((oy * 4 + ky) * 70 + ox * 4) * 64;
    }

    const f32x4 z4 = {0.f, 0.f, 0.f, 0.f};
    f32x4 acc[4] = {z4, z4, z4, z4};

#pragma unroll
    for (int kx = 0; kx < 7; ++kx) {
#pragma unroll
        for (int ci0 = 0; ci0 < 64; ci0 += 32) {
            bf16x8 av = *(const bf16x8*)(wb + kx * 64 + ci0);
#pragma unroll
            for (int s = 0; s < 4; ++s) {
                bf16x8 bv = *(const bf16x8*)(xbase + pixoff[s] + kx * 64 + ci0);
                acc[s] = __builtin_amdgcn_mfma_f32_16x16x32_bf16(av, bv, acc[s], 0, 0, 0);
            }
        }
    }

    float* pb = part + (size_t)(ky * 8 + bc) * 16384;
#pragma unroll
    for (int s = 0; s < 4; ++s) {
        int opix = og * 64 + s * 16 + ml;
#pragma unroll
        for (int r = 0; r < 4; ++r) {
            int co = co0 + 4 * g + r;
            pb[co * 256 + opix] = acc[s][r];
        }
    }
}

// ---------------------------------------------------------------------------
// Reduce 7 ky-partials + bias -> f2/g2. grid = 128, block = 256, float4/thr.
// ---------------------------------------------------------------------------
__global__ __launch_bounds__(256) void conv7_reduce_kernel(
    const float* __restrict__ part, const float* __restrict__ b4,
    const float* __restrict__ b5, float* __restrict__ f2, float* __restrict__ g2)
{
    int idx = (blockIdx.x * 256 + threadIdx.x) * 4;   // over 131072 floats
    int bc = idx >> 14;
    int co = (idx >> 8) & 63;
    int conv = bc & 1, b = bc >> 1;
    int sub = idx & 16383;
    float4 s = make_float4(0.f, 0.f, 0.f, 0.f);
#pragma unroll
    for (int ky = 0; ky < 7; ++ky) {
        float4 v = *(const float4*)&part[(size_t)(ky * 8 + bc) * 16384 + sub];
        s.x += v.x; s.y += v.y; s.z += v.z; s.w += v.w;
    }
    float bias = (conv ? b5 : b4)[co];
    s.x += bias; s.y += bias; s.z += bias; s.w += bias;
    float* y = conv ? g2 : f2;
    *(float4*)&y[(size_t)b * 16384 + sub] = s;
}

// ---------------------------------------------------------------------------
// s2[c,d] = sum_n f2[c,n]*g2[d,n]; beta2 = softmax_c(s2). grid = B, block 256.
// ---------------------------------------------------------------------------
__global__ __launch_bounds__(256) void s2_softmax_kernel(
    const float* __restrict__ f2, const float* __restrict__ g2,
    float* __restrict__ beta2)
{
    __shared__ float f2s[64][65];
    __shared__ __align__(16) float g2t[64][68];   // [n][d]
    __shared__ float s2s[64][65];
    int t = threadIdx.x;
    int b = blockIdx.x;
    int c = t & 63, dg = t >> 6, d0 = dg * 16;

    float acc[16];
#pragma unroll
    for (int k = 0; k < 16; ++k) acc[k] = 0.f;

    for (int r = 0; r < 4; ++r) {
        int nb = r * 64;
        __syncthreads();
        {
            int n = t & 63; int c0 = t >> 6;
#pragma unroll
            for (int k = 0; k < 16; ++k) {
                int cc = c0 * 16 + k;
                f2s[cc][n] = f2[((size_t)(b * 64 + cc) << 8) + nb + n];
                g2t[n][cc] = g2[((size_t)(b * 64 + cc) << 8) + nb + n];
            }
        }
        __syncthreads();
        for (int n = 0; n < 64; ++n) {
            float fvv = f2s[c][n];
#pragma unroll
            for (int jj = 0; jj < 4; ++jj) {
                float4 gv = *reinterpret_cast<const float4*>(&g2t[n][d0 + jj * 4]);
                acc[jj * 4 + 0] = fmaf(fvv, gv.x, acc[jj * 4 + 0]);
                acc[jj * 4 + 1] = fmaf(fvv, gv.y, acc[jj * 4 + 1]);
                acc[jj * 4 + 2] = fmaf(fvv, gv.z, acc[jj * 4 + 2]);
                acc[jj * 4 + 3] = fmaf(fvv, gv.w, acc[jj * 4 + 3]);
            }
        }
    }
    __syncthreads();
#pragma unroll
    for (int k = 0; k < 16; ++k) s2s[c][d0 + k] = acc[k];
    __syncthreads();
    if (t < 64) {
        int d = t;
        float mx = s2s[0][d];
        for (int cc = 1; cc < 64; ++cc) mx = fmaxf(mx, s2s[cc][d]);
        float sm = 0.f;
        for (int cc = 0; cc < 64; ++cc) sm += __expf(s2s[cc][d] - mx);
        float r = 1.f / sm;
        for (int cc = 0; cc < 64; ++cc)
            beta2[((size_t)b << 12) + cc * 64 + d] = __expf(s2s[cc][d] - mx) * r;
    }
}

// ---------------------------------------------------------------------------
// out[b,d,n] = sum_c h2[b,c,n]*beta2[b,c,d] + x[b,d,n]. grid = B*64, block 256.
// ---------------------------------------------------------------------------
__global__ __launch_bounds__(256) void o2_residual_kernel(
    const ushort* __restrict__ h2b, const float* __restrict__ beta2,
    const float* __restrict__ x, float* __restrict__ out)
{
    __shared__ __align__(16) float b2s[64][64];   // [c][d]
    __shared__ float h2s[64][65];
    int t = threadIdx.x;
    int b = blockIdx.x >> 6;
    int n0 = (blockIdx.x & 63) << 6;

    {
#pragma unroll
        for (int k = 0; k < 16; ++k) {
            int idx = k * 256 + t;
            b2s[idx >> 6][idx & 63] = beta2[((size_t)b << 12) + idx];
        }
        int n = t & 63; int c0 = t >> 6;
#pragma unroll
        for (int k = 0; k < 16; ++k) {
            int cc = c0 * 16 + k;
            h2s[cc][n] = bf2f(h2b[((size_t)(b * 64 + cc) << 12) + n0 + n]);
        }
    }
    __syncthreads();

    int n = t & 63, dg = t >> 6, d0 = dg * 16;
    float acc[16];
#pragma unroll
    for (int k = 0; k < 16; ++k) acc[k] = 0.f;

    for (int cc = 0; cc < 64; ++cc) {
        float hv = h2s[cc][n];
#pragma unroll
        for (int jj = 0; jj < 4; ++jj) {
            float4 bv = *reinterpret_cast<const float4*>(&b2s[cc][d0 + jj * 4]);
            acc[jj * 4 + 0] = fmaf(hv, bv.x, acc[jj * 4 + 0]);
            acc[jj * 4 + 1] = fmaf(hv, bv.y, acc[jj * 4 + 1]);
            acc[jj * 4 + 2] = fmaf(hv, bv.z, acc[jj * 4 + 2]);
            acc[jj * 4 + 3] = fmaf(hv, bv.w, acc[jj * 4 + 3]);
        }
    }
#pragma unroll
    for (int k = 0; k < 16; ++k) {
        int d = d0 + k;
        size_t o = ((size_t)(b * 64 + d) << 12) + n0 + n;
        out[o] = acc[k] + x[o];
    }
}

// ---------------------------------------------------------------------------
extern "C" void kernel_launch(void* const* d_in, const int* in_sizes, int n_in,
                              void* d_out, int out_size, void* d_ws, size_t ws_size,
                              hipStream_t stream)
{
    const float* x  = (const float*)d_in[0];
    const float* w1 = (const float*)d_in[1];
    const float* b1 = (const float*)d_in[2];
    const float* w2 = (const float*)d_in[3];
    const float* b2 = (const float*)d_in[4];
    const float* w3 = (const float*)d_in[5];
    const float* b3 = (const float*)d_in[6];
    const float* w4 = (const float*)d_in[7];
    const float* b4 = (const float*)d_in[8];
    const float* w5 = (const float*)d_in[9];
    const float* b5 = (const float*)d_in[10];
    const float* w6 = (const float*)d_in[11];
    const float* b6 = (const float*)d_in[12];
    float* out = (float*)d_out;

    ushort* u = (ushort*)d_ws;
    ushort* fT  = u;                  // 131072 elems
    ushort* gT  = fT + 131072;        // 131072
    ushort* hhb = gT + 131072;        // 1048576
    ushort* x2p = hhb + 1048576;      // 1254400 (4*70*70*64), padded
    ushort* h2b = x2p + 1254400;      // 1048576
    ushort* Wt  = h2b + 1048576;      // 401408 (2*64*49*64)
    float* fr    = (float*)(Wt + 401408);
    float* f2    = fr;                // 65536
    float* g2    = fr + 65536;        // 65536
    float* beta2 = fr + 131072;       // 16384
    float* part  = fr + 147456;       // 917504 (7*8*64*256)

    produce_fgh<<<256, 256, 0, stream>>>(x, w1, b1, w2, b2, w3, b3, fT, gT, hhb);
    wt_kernel<<<128, 256, 0, stream>>>(w4, w5, Wt);
    zero_halo_kernel<<<13, 256, 0, stream>>>(x2p);
    attn_kernel<<<256, 1024, 0, stream>>>(fT, gT, hhb, w6, b6, x2p, h2b);
    conv7_split_kernel<<<224, 256, 0, stream>>>(x2p, Wt, part);
    conv7_reduce_kernel<<<128, 256, 0, stream>>>(part, b4, b5, f2, g2);
    s2_softmax_kernel<<<BB, 256, 0, stream>>>(f2, g2, beta2);
    o2_residual_kernel<<<256, 256, 0, stream>>>(h2b, beta2, x, out);
}

// Round 7
// 86.221 us; speedup vs baseline: 6.5185x; 1.2195x over previous
//
#include <hip/hip_runtime.h>
#include <math.h>

#define BB 4
#define CC 64
#define CRR 8
#define NN 4096

typedef __attribute__((ext_vector_type(8))) short bf16x8;
typedef __attribute__((ext_vector_type(4))) float f32x4;

__device__ inline float bf2f(ushort u) {
    union { uint i; float f; } v; v.i = (uint)u << 16; return v.f;
}
__device__ inline ushort f2bf(float f) {
    uint u = __builtin_bit_cast(uint, f);
    u = (u + 0x7FFFu + ((u >> 16) & 1u)) >> 16;
    return (ushort)u;
}
__device__ inline uint bfpack2(float a, float b) {
    uint ua = __builtin_bit_cast(uint, a);
    uint ub = __builtin_bit_cast(uint, b);
    ua = (ua + 0x7FFFu + ((ua >> 16) & 1u)) >> 16;
    ub = (ub + 0x7FFFu + ((ub >> 16) & 1u)) & 0xFFFF0000u;
    return ua | ub;
}
// 1-op truncating bf16 pair pack: bytes [b.3,b.2,a.3,a.2]
__device__ inline uint pkrtz(float a, float b) {
    return __builtin_amdgcn_perm(__builtin_bit_cast(uint, b),
                                 __builtin_bit_cast(uint, a), 0x07060302u);
}
__device__ inline float fexp2(float x) { return exp2f(x); }

// x2p padded pixel-major: [b][py 70][px 70][ci 64] bf16, pad=3
#define X2P_B 313600   // 70*70*64

// ---------------------------------------------------------------------------
// Producer: f = conv1x1(x,w1,b1) * log2(e), g = conv1x1(x,w2,b2),
//           hh = conv1x1(x,w3,b3).  b = bid&3 (XCD-local batches).
// ---------------------------------------------------------------------------
__global__ __launch_bounds__(256) void produce_fgh(
    const float* __restrict__ x,
    const float* __restrict__ w1, const float* __restrict__ b1,
    const float* __restrict__ w2, const float* __restrict__ b2,
    const float* __restrict__ w3, const float* __restrict__ b3,
    ushort* __restrict__ fT, ushort* __restrict__ gT, ushort* __restrict__ hhb)
{
    const float LOG2E = 1.4426950408889634f;
    int t = threadIdx.x;
    int b = blockIdx.x & 3;
    int n = ((blockIdx.x >> 2) << 6) + (t & 63);
    int og = __builtin_amdgcn_readfirstlane(t >> 6);  // wave-uniform

    const float* xb = x + ((size_t)b << 18) + n;
    float xv[64];
#pragma unroll
    for (int c = 0; c < 64; ++c) xv[c] = xb[(size_t)c << 12];

    if (og == 0) {
        ushort fo[8], go[8];
#pragma unroll
        for (int k = 0; k < 8; ++k) {
            float a1 = b1[k], a2 = b2[k];
#pragma unroll
            for (int c = 0; c < 64; ++c) {
                a1 = fmaf(w1[k * 64 + c], xv[c], a1);
                a2 = fmaf(w2[k * 64 + c], xv[c], a2);
            }
            fo[k] = f2bf(a1 * LOG2E); go[k] = f2bf(a2);
        }
        uint4 fq = make_uint4((uint)fo[0] | ((uint)fo[1] << 16),
                              (uint)fo[2] | ((uint)fo[3] << 16),
                              (uint)fo[4] | ((uint)fo[5] << 16),
                              (uint)fo[6] | ((uint)fo[7] << 16));
        uint4 gq = make_uint4((uint)go[0] | ((uint)go[1] << 16),
                              (uint)go[2] | ((uint)go[3] << 16),
                              (uint)go[4] | ((uint)go[5] << 16),
                              (uint)go[6] | ((uint)go[7] << 16));
        *(uint4*)&fT[((size_t)b << 15) + (size_t)n * 8] = fq;
        *(uint4*)&gT[((size_t)b << 15) + (size_t)n * 8] = gq;
#pragma unroll
        for (int k = 0; k < 4; ++k) {
            float a = b3[k];
#pragma unroll
            for (int c = 0; c < 64; ++c) a = fmaf(w3[k * 64 + c], xv[c], a);
            hhb[((size_t)b << 18) + ((size_t)k << 12) + n] = f2bf(a);
        }
    } else {
        int c0 = og * 20 - 16;  // 4, 24, 44
#pragma unroll
        for (int k = 0; k < 20; ++k) {
            float a = b3[c0 + k];
#pragma unroll
            for (int c = 0; c < 64; ++c) a = fmaf(w3[(c0 + k) * 64 + c], xv[c], a);
            hhb[((size_t)b << 18) + ((size_t)(c0 + k) << 12) + n] = f2bf(a);
        }
    }
}

// ---------------------------------------------------------------------------
// Weight transform + w6->bf16 + x2p halo zero, one kernel.
// blocks 0..127: Wt[conv][co][kk][ci]; block 128: w6b; 129..141: halo.
// ---------------------------------------------------------------------------
__global__ __launch_bounds__(256) void wtz_kernel(
    const float* __restrict__ w4, const float* __restrict__ w5,
    const float* __restrict__ w6,
    ushort* __restrict__ Wt, ushort* __restrict__ w6b, ushort* __restrict__ x2p)
{
    int bid = blockIdx.x;
    int t = threadIdx.x;
    if (bid < 128) {
        int conv = bid >> 6, co = bid & 63;
        const float* W = conv ? w5 : w4;
        for (int i = t; i < 3136; i += 256) {
            int ci = i / 49, kk = i - ci * 49;
            Wt[(((size_t)(conv * 64 + co)) * 49 + kk) * 64 + ci] = f2bf(W[co * 3136 + i]);
        }
    } else if (bid == 128) {
#pragma unroll
        for (int k = 0; k < 16; ++k) {
            int i = k * 256 + t;
            w6b[i] = f2bf(w6[i]);
        }
    } else {
        int gid = (bid - 129) * 256 + t;
        if (gid >= 4 * 804) return;
        int b = gid / 804;
        int i = gid - b * 804;
        int py, px;
        if (i < 210) { py = i / 70; px = i - py * 70; }
        else if (i < 420) { int j = i - 210; int r = j / 70; py = 67 + r; px = j - r * 70; }
        else { int j = i - 420; int r = j / 6; py = 3 + r; int c = j - r * 6; px = c < 3 ? c : 64 + c; }
        ushort* p = x2p + (size_t)b * X2P_B + (size_t)(py * 70 + px) * 64;
        uint4 z = make_uint4(0, 0, 0, 0);
#pragma unroll
        for (int k = 0; k < 8; ++k) *(uint4*)(p + k * 8) = z;
    }
}

// ---------------------------------------------------------------------------
// Fused MFMA flash attention + h2 epilogue. 1024 threads = 16 waves =
// 4 n-split quads x 4 m-strips. Fixed-base exp2 softmax. b = bid&3.
// ---------------------------------------------------------------------------
__global__ __launch_bounds__(1024) void attn_kernel(
    const ushort* __restrict__ fT, const ushort* __restrict__ gT,
    const ushort* __restrict__ hhb, const ushort* __restrict__ w6b,
    const float* __restrict__ b6,
    ushort* __restrict__ x2p, ushort* __restrict__ h2b)
{
    __shared__ __align__(16) char smem[98304];
    ushort* hhT = (ushort*)smem;                 // [4 quad][2 buf][4096]  64 KB
    ushort* PstB = (ushort*)(smem + 65536);      // [16 wave][1024]        32 KB
    float* Acc = (float*)smem;                   // [4 q][64 m][68] (combine)
    float* Lq  = (float*)(smem + 69632);         // [4][64]
    ushort* x2s = (ushort*)(smem + 70656);       // [64 m][72]

    int t = threadIdx.x;
    int q = t >> 8, tq = t & 255;
    int l = t & 63;
    int wq = tq >> 6;
    int w16 = t >> 6;
    int ml = l & 15, g = l >> 4;
    int b = blockIdx.x & 3;                      // XCD-local batch
    int mt = blockIdx.x >> 2;
    int m0 = mt << 6;
    int col = m0 + wq * 16 + ml;

    const ushort* fTb = fT + ((size_t)b << 15) + (size_t)q * 8192;
    const ushort* gTb = gT + ((size_t)b << 15);
    const ushort* hhB = hhb + ((size_t)b << 18) + (q << 10);

    const bf16x8 z8 = {0, 0, 0, 0, 0, 0, 0, 0};
    const f32x4 z4 = {0.f, 0.f, 0.f, 0.f};

    bf16x8 gfrag = *(const bf16x8*)(gTb + (size_t)col * 8);
    if (g != 0) gfrag = z8;

    int sc = tq >> 2, sp = tq & 3;
    const ushort* hrowBase = hhB + (size_t)sc * 4096 + sp * 16;
    int hdst = q * 8192 + sp * 1024 + sc * 8;

    uint4 h0 = *(const uint4*)(hrowBase);
    uint4 h1 = *(const uint4*)(hrowBase + 8);
    *(uint4*)&hhT[hdst] = h0;
    *(uint4*)&hhT[hdst + 512] = h1;
    bf16x8 afc[4];
#pragma unroll
    for (int s = 0; s < 4; ++s)
        afc[s] = *(const bf16x8*)(fTb + (size_t)(16 * s + ml) * 8);

    f32x4 acc[4] = {z4, z4, z4, z4};
    float rsum = 0.f;
    int swz = (ml & 7) << 4;
    char* pbase = (char*)PstB + w16 * 2048;
    __syncthreads();

    for (int nt = 0; nt < 16; ++nt) {
        int buf = nt & 1;
        bf16x8 afn[4];
        if (nt < 15) {
            int n0 = (nt + 1) << 6;
            h0 = *(const uint4*)(hrowBase + n0);
            h1 = *(const uint4*)(hrowBase + n0 + 8);
#pragma unroll
            for (int s = 0; s < 4; ++s)
                afn[s] = *(const bf16x8*)(fTb + (size_t)(n0 + 16 * s + ml) * 8);
        }

        // ---- scores (f pre-scaled by log2e) ----
        f32x4 Sv[4];
#pragma unroll
        for (int s = 0; s < 4; ++s)
            Sv[s] = __builtin_amdgcn_mfma_f32_16x16x32_bf16(afc[s], gfrag, z4, 0, 0, 0);

        // ---- P = 2^s; pack with single v_perm (RTZ) ----
        uint plo[4], phi[4];
#pragma unroll
        for (int s = 0; s < 4; ++s) {
            float p0 = fexp2(Sv[s][0]);
            float p1 = fexp2(Sv[s][1]);
            float p2 = fexp2(Sv[s][2]);
            float p3 = fexp2(Sv[s][3]);
            rsum += (p0 + p1) + (p2 + p3);
            plo[s] = pkrtz(p0, p1);
            phi[s] = pkrtz(p2, p3);
        }

#pragma unroll
        for (int s = 0; s < 4; ++s) {
            uint off = (uint)((ml * 128 + 32 * s + 8 * g) ^ swz);
            *(uint2*)(pbase + off) = make_uint2(plo[s], phi[s]);
        }

        // ---- PV ----
#pragma unroll
        for (int kk = 0; kk < 2; ++kk) {
            uint off = (uint)((ml * 128 + 64 * kk + 16 * g) ^ swz);
            bf16x8 pf = *(const bf16x8*)(pbase + off);
#pragma unroll
            for (int ct = 0; ct < 4; ++ct) {
                bf16x8 hf = *(const bf16x8*)&hhT[q * 8192 + buf * 4096 + (kk * 4 + g) * 512 + (16 * ct + ml) * 8];
                acc[ct] = __builtin_amdgcn_mfma_f32_16x16x32_bf16(hf, pf, acc[ct], 0, 0, 0);
            }
        }

        if (nt < 15) {
            int nb = (nt + 1) & 1;
            *(uint4*)&hhT[hdst + nb * 4096] = h0;
            *(uint4*)&hhT[hdst + nb * 4096 + 512] = h1;
#pragma unroll
            for (int s = 0; s < 4; ++s) afc[s] = afn[s];
        }
        __syncthreads();
    }

    rsum += __shfl_xor(rsum, 16);
    rsum += __shfl_xor(rsum, 32);

    {
        float* arow = Acc + q * 4352 + (wq * 16 + ml) * 68;
#pragma unroll
        for (int ct = 0; ct < 4; ++ct)
            *(f32x4*)(arow + 16 * ct + 4 * g) = acc[ct];
        if (g == 0) Lq[q * 64 + wq * 16 + ml] = rsum;
    }
    __syncthreads();

    {
        int m = t >> 4, c0 = (t & 15) << 2;
        float Ltot = Lq[m] + Lq[64 + m] + Lq[128 + m] + Lq[192 + m];
        float rL = 1.f / Ltot;
        f32x4 v0 = *(const f32x4*)(Acc + 0 * 4352 + m * 68 + c0);
        f32x4 v1 = *(const f32x4*)(Acc + 1 * 4352 + m * 68 + c0);
        f32x4 v2 = *(const f32x4*)(Acc + 2 * 4352 + m * 68 + c0);
        f32x4 v3 = *(const f32x4*)(Acc + 3 * 4352 + m * 68 + c0);
        f32x4 v;
#pragma unroll
        for (int r = 0; r < 4; ++r)
            v[r] = ((v0[r] + v1[r]) + (v2[r] + v3[r])) * rL;
        uint2 pk = make_uint2(bfpack2(v[0], v[1]), bfpack2(v[2], v[3]));
        int px = m + 3, py = mt + 3;
        *(uint2*)(x2p + (size_t)b * X2P_B + (size_t)(py * 70 + px) * 64 + c0) = pk;
        *(uint2*)(x2s + m * 72 + c0) = pk;
    }
    __syncthreads();

    {
        int dt = w16 & 3, mq = w16 >> 2;
        f32x4 hacc = z4;
#pragma unroll
        for (int kk = 0; kk < 2; ++kk) {
            bf16x8 xf = *(const bf16x8*)(x2s + (mq * 16 + ml) * 72 + 32 * kk + 8 * g);
            bf16x8 wf = *(const bf16x8*)(w6b + (size_t)(16 * dt + ml) * 64 + 32 * kk + 8 * g);
            hacc = __builtin_amdgcn_mfma_f32_16x16x32_bf16(wf, xf, hacc, 0, 0, 0);
        }
        ushort* h2row = h2b + ((size_t)b << 18) + (m0 + mq * 16 + ml);
#pragma unroll
        for (int r = 0; r < 4; ++r) {
            int d = 16 * dt + 4 * g + r;
            h2row[(size_t)d << 12] = f2bf(hacc[r] + b6[d]);
        }
    }
}

// ---------------------------------------------------------------------------
// 7x7 stride-4 conv, ky-split implicit GEMM, XCD-chunked: bc = bid&7 so each
// XCD keeps one x2p image L2-resident. grid = 224 wgs (896 waves).
// ---------------------------------------------------------------------------
__global__ __launch_bounds__(256) void conv7_split_kernel(
    const ushort* __restrict__ x2p, const ushort* __restrict__ Wt,
    float* __restrict__ part)
{
    int t = threadIdx.x;
    int l = t & 63, w = t >> 6;
    int ml = l & 15, g = l >> 4;
    int lb = (blockIdx.x & 7) * 28 + (blockIdx.x >> 3);   // bijective, 224
    int bc = lb / 28;                     // XCD-local (b,conv)
    int idx = (lb % 28) * 4 + w;          // 0..111
    int ky = idx >> 4;
    int ct = (idx >> 2) & 3;
    int og = idx & 3;
    int conv = bc & 1, b = bc >> 1;

    int co0 = ct * 16;
    const ushort* wb = Wt + (size_t)conv * 200704
                     + (size_t)(co0 + ml) * 3136 + (size_t)(ky * 7) * 64 + g * 8;
    const ushort* xbase = x2p + (size_t)b * X2P_B + g * 8;

    int pixoff[4];
#pragma unroll
    for (int s = 0; s < 4; ++s) {
        int opix = og * 64 + s * 16 + ml;
        int oy = opix >> 4, ox = opix & 15;
        pixoff[s] = ((oy * 4 + ky) * 70 + ox * 4) * 64;
    }

    const f32x4 z4 = {0.f, 0.f, 0.f, 0.f};
    f32x4 acc[4] = {z4, z4, z4, z4};

#pragma unroll
    for (int kx = 0; kx < 7; ++kx) {
#pragma unroll
        for (int ci0 = 0; ci0 < 64; ci0 += 32) {
            bf16x8 av = *(const bf16x8*)(wb + kx * 64 + ci0);
#pragma unroll
            for (int s = 0; s < 4; ++s) {
                bf16x8 bv = *(const bf16x8*)(xbase + pixoff[s] + kx * 64 + ci0);
                acc[s] = __builtin_amdgcn_mfma_f32_16x16x32_bf16(av, bv, acc[s], 0, 0, 0);
            }
        }
    }

    float* pb = part + (size_t)(ky * 8 + bc) * 16384;
#pragma unroll
    for (int s = 0; s < 4; ++s) {
        int opix = og * 64 + s * 16 + ml;
#pragma unroll
        for (int r = 0; r < 4; ++r) {
            int co = co0 + 4 * g + r;
            pb[co * 256 + opix] = acc[s][r];
        }
    }
}

// ---------------------------------------------------------------------------
// Reduce 7 ky-partials + bias -> f2/g2. grid = 128, block = 256, float4/thr.
// ---------------------------------------------------------------------------
__global__ __launch_bounds__(256) void conv7_reduce_kernel(
    const float* __restrict__ part, const float* __restrict__ b4,
    const float* __restrict__ b5, float* __restrict__ f2, float* __restrict__ g2)
{
    int idx = (blockIdx.x * 256 + threadIdx.x) * 4;
    int bc = idx >> 14;
    int co = (idx >> 8) & 63;
    int conv = bc & 1, b = bc >> 1;
    int sub = idx & 16383;
    float4 s = make_float4(0.f, 0.f, 0.f, 0.f);
#pragma unroll
    for (int ky = 0; ky < 7; ++ky) {
        float4 v = *(const float4*)&part[(size_t)(ky * 8 + bc) * 16384 + sub];
        s.x += v.x; s.y += v.y; s.z += v.z; s.w += v.w;
    }
    float bias = (conv ? b5 : b4)[co];
    s.x += bias; s.y += bias; s.z += bias; s.w += bias;
    float* y = conv ? g2 : f2;
    *(float4*)&y[(size_t)b * 16384 + sub] = s;
}

// ---------------------------------------------------------------------------
// s2[c,d] = sum_n f2[c,n]*g2[d,n]; beta2 = softmax_c(s2).
// grid = B, block = 1024 (4 n-chunk quads), fp32 throughout.
// ---------------------------------------------------------------------------
__global__ __launch_bounds__(1024) void s2_softmax_kernel(
    const float* __restrict__ f2, const float* __restrict__ g2,
    float* __restrict__ beta2)
{
    __shared__ __align__(16) float g2t[4][64][68];   // 69,632 B; reused as partials
    __shared__ __align__(16) float s2f[64][68];      // 17,408 B
    __shared__ float red[6][64];
    int t = threadIdx.x;
    int b = blockIdx.x;
    int q = t >> 8, tq = t & 255;
    int nb = q * 64;

    {   // stage g2 chunk transposed: g2t[q][n][cc]
        int n = tq & 63, c0 = tq >> 6;
#pragma unroll
        for (int k = 0; k < 16; ++k) {
            int cc = c0 * 16 + k;
            g2t[q][n][cc] = g2[((size_t)(b * 64 + cc) << 8) + nb + n];
        }
    }
    __syncthreads();

    int c = tq & 63, dq = tq >> 6, d0 = dq * 16;
    float acc[16];
#pragma unroll
    for (int k = 0; k < 16; ++k) acc[k] = 0.f;
    const float* frow = f2 + ((size_t)(b * 64 + c) << 8) + nb;
#pragma unroll 4
    for (int n = 0; n < 64; ++n) {
        float fv = frow[n];
#pragma unroll
        for (int jj = 0; jj < 4; ++jj) {
            float4 gv = *(const float4*)&g2t[q][n][d0 + jj * 4];
            acc[jj * 4 + 0] = fmaf(fv, gv.x, acc[jj * 4 + 0]);
            acc[jj * 4 + 1] = fmaf(fv, gv.y, acc[jj * 4 + 1]);
            acc[jj * 4 + 2] = fmaf(fv, gv.z, acc[jj * 4 + 2]);
            acc[jj * 4 + 3] = fmaf(fv, gv.w, acc[jj * 4 + 3]);
        }
    }
    __syncthreads();
    // partials into g2t region: part[q][c][d]
    float* part = &g2t[0][0][0];
#pragma unroll
    for (int k = 0; k < 16; ++k) part[q * 4096 + c * 64 + d0 + k] = acc[k];
    __syncthreads();
    {   // combine quads: 4 cells per thread
        int idx = t * 4;
        int cc = idx >> 6, dd = idx & 63;
        float4 s0 = *(const float4*)&part[cc * 64 + dd];
        float4 s1 = *(const float4*)&part[4096 + cc * 64 + dd];
        float4 s2v = *(const float4*)&part[8192 + cc * 64 + dd];
        float4 s3 = *(const float4*)&part[12288 + cc * 64 + dd];
        float4 s;
        s.x = (s0.x + s1.x) + (s2v.x + s3.x);
        s.y = (s0.y + s1.y) + (s2v.y + s3.y);
        s.z = (s0.z + s1.z) + (s2v.z + s3.z);
        s.w = (s0.w + s1.w) + (s2v.w + s3.w);
        *(float4*)&s2f[cc][dd] = s;
    }
    __syncthreads();
    // softmax over c (dim 1), per d
    if (t < 256) {
        int d = t & 63, cq = t >> 6;
        float mx = -3e38f;
#pragma unroll
        for (int k = 0; k < 16; ++k) mx = fmaxf(mx, s2f[cq * 16 + k][d]);
        red[cq][d] = mx;
    }
    __syncthreads();
    if (t < 64)
        red[4][t] = fmaxf(fmaxf(red[0][t], red[1][t]), fmaxf(red[2][t], red[3][t]));
    __syncthreads();
    if (t < 256) {
        int d = t & 63, cq = t >> 6;
        float mx = red[4][d];
        float s = 0.f;
#pragma unroll
        for (int k = 0; k < 16; ++k) s += __expf(s2f[cq * 16 + k][d] - mx);
        red[cq][d] = s;   // rows 0-3 reused (post-barrier)
    }
    __syncthreads();
    if (t < 64)
        red[5][t] = 1.f / ((red[0][t] + red[1][t]) + (red[2][t] + red[3][t]));
    __syncthreads();
    if (t < 256) {
        int d = t & 63, cq = t >> 6;
        float mx = red[4][d], r = red[5][d];
#pragma unroll
        for (int k = 0; k < 16; ++k) {
            int cc = cq * 16 + k;
            beta2[((size_t)b << 12) + cc * 64 + d] = __expf(s2f[cc][d] - mx) * r;
        }
    }
}

// ---------------------------------------------------------------------------
// out[b,d,n] = sum_c h2[b,c,n]*beta2[b,c,d] + x[b,d,n]. b = bid&3.
// ---------------------------------------------------------------------------
__global__ __launch_bounds__(256) void o2_residual_kernel(
    const ushort* __restrict__ h2b, const float* __restrict__ beta2,
    const float* __restrict__ x, float* __restrict__ out)
{
    __shared__ __align__(16) float b2s[64][64];   // [c][d]
    __shared__ float h2s[64][65];
    int t = threadIdx.x;
    int b = blockIdx.x & 3;
    int n0 = (blockIdx.x >> 2) << 6;

    {
#pragma unroll
        for (int k = 0; k < 16; ++k) {
            int idx = k * 256 + t;
            b2s[idx >> 6][idx & 63] = beta2[((size_t)b << 12) + idx];
        }
        int n = t & 63; int c0 = t >> 6;
#pragma unroll
        for (int k = 0; k < 16; ++k) {
            int cc = c0 * 16 + k;
            h2s[cc][n] = bf2f(h2b[((size_t)(b * 64 + cc) << 12) + n0 + n]);
        }
    }
    __syncthreads();

    int n = t & 63, dg = t >> 6, d0 = dg * 16;
    float acc[16];
#pragma unroll
    for (int k = 0; k < 16; ++k) acc[k] = 0.f;

    for (int cc = 0; cc < 64; ++cc) {
        float hv = h2s[cc][n];
#pragma unroll
        for (int jj = 0; jj < 4; ++jj) {
            float4 bv = *reinterpret_cast<const float4*>(&b2s[cc][d0 + jj * 4]);
            acc[jj * 4 + 0] = fmaf(hv, bv.x, acc[jj * 4 + 0]);
            acc[jj * 4 + 1] = fmaf(hv, bv.y, acc[jj * 4 + 1]);
            acc[jj * 4 + 2] = fmaf(hv, bv.z, acc[jj * 4 + 2]);
            acc[jj * 4 + 3] = fmaf(hv, bv.w, acc[jj * 4 + 3]);
        }
    }
#pragma unroll
    for (int k = 0; k < 16; ++k) {
        int d = d0 + k;
        size_t o = ((size_t)(b * 64 + d) << 12) + n0 + n;
        out[o] = acc[k] + x[o];
    }
}

// ---------------------------------------------------------------------------
extern "C" void kernel_launch(void* const* d_in, const int* in_sizes, int n_in,
                              void* d_out, int out_size, void* d_ws, size_t ws_size,
                              hipStream_t stream)
{
    const float* x  = (const float*)d_in[0];
    const float* w1 = (const float*)d_in[1];
    const float* b1 = (const float*)d_in[2];
    const float* w2 = (const float*)d_in[3];
    const float* b2 = (const float*)d_in[4];
    const float* w3 = (const float*)d_in[5];
    const float* b3 = (const float*)d_in[6];
    const float* w4 = (const float*)d_in[7];
    const float* b4 = (const float*)d_in[8];
    const float* w5 = (const float*)d_in[9];
    const float* b5 = (const float*)d_in[10];
    const float* w6 = (const float*)d_in[11];
    const float* b6 = (const float*)d_in[12];
    float* out = (float*)d_out;

    ushort* u = (ushort*)d_ws;
    ushort* fT  = u;                  // 131072 elems
    ushort* gT  = fT + 131072;        // 131072
    ushort* hhb = gT + 131072;        // 1048576
    ushort* x2p = hhb + 1048576;      // 1254400 (4*70*70*64), padded
    ushort* h2b = x2p + 1254400;      // 1048576
    ushort* Wt  = h2b + 1048576;      // 401408 (2*64*49*64)
    ushort* w6b = Wt + 401408;        // 4096
    float* fr    = (float*)(w6b + 4096);
    float* f2    = fr;                // 65536
    float* g2    = fr + 65536;        // 65536
    float* beta2 = fr + 131072;       // 16384
    float* part  = fr + 147456;       // 917504 (7*8*64*256)

    produce_fgh<<<256, 256, 0, stream>>>(x, w1, b1, w2, b2, w3, b3, fT, gT, hhb);
    wtz_kernel<<<142, 256, 0, stream>>>(w4, w5, w6, Wt, w6b, x2p);
    attn_kernel<<<256, 1024, 0, stream>>>(fT, gT, hhb, w6b, b6, x2p, h2b);
    conv7_split_kernel<<<224, 256, 0, stream>>>(x2p, Wt, part);
    conv7_reduce_kernel<<<128, 256, 0, stream>>>(part, b4, b5, f2, g2);
    s2_softmax_kernel<<<BB, 1024, 0, stream>>>(f2, g2, beta2);
    o2_residual_kernel<<<256, 256, 0, stream>>>(h2b, beta2, x, out);
}